// Round 1
// baseline (3997.859 us; speedup 1.0000x reference)
//
#include <hip/hip_runtime.h>
#include <hip/hip_bf16.h>
#include <math.h>

#define EMBED 1024
#define LSEQ 4096
#define BATCH 2
#define ZD 128
#define CHUNKC 2048
#define NSTATE 16
#define DTR 64
#define XDBL_W 96   // DT_RANK + 2*DSTATE

__device__ __forceinline__ float sigmoidf_(float x){ return 1.f/(1.f+__expf(-x)); }
__device__ __forceinline__ float siluf_(float x){ return x/(1.f+__expf(-x)); }

// ---------------------------------------------------------------- rmsnorm
__global__ __launch_bounds__(256) void rmsnorm_k(const float* __restrict__ x,
                                                 const float* __restrict__ w,
                                                 float* __restrict__ xn) {
  size_t row = blockIdx.x;
  const float* px = x + row*EMBED;
  float* po = xn + row*EMBED;
  int tid = threadIdx.x;
  float4 xv = *(const float4*)(px + tid*4);
  float ss = xv.x*xv.x + xv.y*xv.y + xv.z*xv.z + xv.w*xv.w;
  #pragma unroll
  for (int off=32; off; off>>=1) ss += __shfl_down(ss, off, 64);
  __shared__ float red[4];
  if ((tid&63)==0) red[tid>>6]=ss;
  __syncthreads();
  float tot = red[0]+red[1]+red[2]+red[3];
  float scale = rsqrtf(tot*(1.f/EMBED) + 1e-5f);
  float4 wv = *(const float4*)(w + tid*4);
  float4 o;
  o.x=xv.x*scale*wv.x; o.y=xv.y*scale*wv.y; o.z=xv.z*scale*wv.z; o.w=xv.w*scale*wv.w;
  *(float4*)(po + tid*4) = o;
}

// ---------------------------------------------------------------- gtab (Toeplitz rel-pos bias)
// bias[q,k] = sum_j P_j*cos(d*f_j) - Q_j*sin(d*f_j), d = q-k >= 0
__global__ __launch_bounds__(256) void gtab_k(const float* __restrict__ alpha,
                                              const float* __restrict__ beta,
                                              float* __restrict__ gtab) {
  __shared__ float P[64], Q[64], F[64];
  int tid = threadIdx.x;
  if (tid < 64) {
    float a1=alpha[tid], a2=alpha[64+tid], b1=beta[tid], b2=beta[64+tid];
    P[tid]=a1*b1+a2*b2;
    Q[tid]=a2*b1-a1*b2;
    F[tid]=expf(-0.14391156831f*(float)tid); // ln(10000)/64
  }
  __syncthreads();
  int d = blockIdx.x*256 + tid;
  if (d < CHUNKC) {
    float s=0.f;
    for (int j=0;j<64;++j){
      float th = (float)d * F[j];
      float sn, cs;
      sincosf(th, &sn, &cs);
      s += P[j]*cs - Q[j]*sn;
    }
    gtab[d]=s;
  }
}

// ---------------------------------------------------------------- S6 scan
__global__ __launch_bounds__(256) void scan_k(const float* __restrict__ xdbl,
                                              const float* __restrict__ dtv,
                                              const float* __restrict__ xn,
                                              const float* __restrict__ A_log,
                                              const float* __restrict__ D_p,
                                              float* __restrict__ mx) {
  int b = blockIdx.x >> 2;
  int d = ((blockIdx.x & 3) << 8) + threadIdx.x;
  int tid = threadIdx.x;
  float A[NSTATE], h[NSTATE];
  #pragma unroll
  for (int n=0;n<NSTATE;++n){ A[n] = -__expf(A_log[(size_t)d*NSTATE+n]); h[n]=0.f; }
  float Dp = D_p[d];
  __shared__ float BCb[8][32];
  const float* xd  = xdbl + (size_t)b*LSEQ*XDBL_W + DTR;
  const float* pdt = dtv + (size_t)b*LSEQ*EMBED + d;
  const float* pu  = xn  + (size_t)b*LSEQ*EMBED + d;
  float* pmx = mx + (size_t)b*LSEQ*EMBED + d;
  for (int t0=0; t0<LSEQ; t0+=8) {
    __syncthreads();
    { int tt = tid>>5, jj = tid&31;
      BCb[tt][jj] = xd[(size_t)(t0+tt)*XDBL_W + jj]; }
    __syncthreads();
    #pragma unroll
    for (int tt=0; tt<8; ++tt) {
      int t = t0 + tt;
      float dtt = pdt[(size_t)t*EMBED];
      float ut  = pu[(size_t)t*EMBED];
      float du = dtt*ut;
      float y = 0.f;
      #pragma unroll
      for (int n=0;n<NSTATE;++n){
        float dA = __expf(dtt*A[n]);
        h[n] = dA*h[n] + du*BCb[tt][n];
        y += h[n]*BCb[tt][16+n];
      }
      pmx[(size_t)t*EMBED] = siluf_(y + ut*Dp);
    }
  }
}

// ---------------------------------------------------------------- row softmax (2048 wide)
__global__ __launch_bounds__(256) void softmax_k(float* __restrict__ S) {
  size_t row = blockIdx.x;
  float* p = S + row*CHUNKC;
  int tid = threadIdx.x;
  float v[8];
  float m = -1e30f;
  #pragma unroll
  for (int i=0;i<8;++i){ v[i]=p[tid + i*256]; m=fmaxf(m,v[i]); }
  #pragma unroll
  for (int off=32; off; off>>=1) m = fmaxf(m, __shfl_down(m, off, 64));
  __shared__ float red[4];
  if ((tid&63)==0) red[tid>>6]=m;
  __syncthreads();
  m = fmaxf(fmaxf(red[0],red[1]),fmaxf(red[2],red[3]));
  float s=0.f;
  #pragma unroll
  for (int i=0;i<8;++i){ v[i]=__expf(v[i]-m); s+=v[i]; }
  #pragma unroll
  for (int off=32; off; off>>=1) s += __shfl_down(s, off, 64);
  __syncthreads();
  if ((tid&63)==0) red[tid>>6]=s;
  __syncthreads();
  s = red[0]+red[1]+red[2]+red[3];
  float inv = 1.f/s;
  #pragma unroll
  for (int i=0;i<8;++i) p[tid + i*256] = v[i]*inv;
}

// ---------------------------------------------------------------- generic tiled GEMM
// C[m,n] = sum_k A[m,k] * B'[k,n]; BT=true: B is (N,K) row-major (dot of rows)
// EPI: 0 raw, 1 silu+bias, 2 softplus+bias, 3 base-split, 4 qk bias+mask, 5 final gate
struct EpiParams {
  const float* bias;
  const float* gtab;
  const float* gamma;
  const float* beta2;
  float* u_out; float* q_out; float* k_out; float* r_out; float* hx_out;
  const float* hx_in; const float* u_in; const float* resid;
  float* out_p;
};

#define BM 64
#define BN 64
#define BKK 16

template<int EPI, bool BT, bool A2MUL>
__global__ __launch_bounds__(256) void gemm_k(
    const float* __restrict__ A, int lda,
    const float* __restrict__ A2,
    const float* __restrict__ Bp, int ldb,
    float* __restrict__ C, int ldc,
    int M, int N, int K, EpiParams ep)
{
  __shared__ float As[BKK][BM+4];
  __shared__ float Bs[BKK][BN+4];
  int tid = threadIdx.x;
  int m0 = blockIdx.y*BM, n0 = blockIdx.x*BN;
  float acc[4][4] = {};
  int tx = tid & 15, ty = tid >> 4;
  int lr  = tid >> 2;        // 0..63
  int lc4 = (tid & 3) * 4;   // 0,4,8,12

  for (int k0 = 0; k0 < K; k0 += BKK) {
    // A tile (64 rows x 16 k), transposed store
    {
      const float* src = A + (size_t)(m0+lr)*lda + k0 + lc4;
      float4 av = *(const float4*)src;
      if constexpr (A2MUL) {
        float4 a2 = *(const float4*)(A2 + (size_t)(m0+lr)*lda + k0 + lc4);
        av.x*=a2.x; av.y*=a2.y; av.z*=a2.z; av.w*=a2.w;
      }
      As[lc4+0][lr]=av.x; As[lc4+1][lr]=av.y; As[lc4+2][lr]=av.z; As[lc4+3][lr]=av.w;
    }
    if constexpr (BT) {
      int nn = n0 + lr;
      float4 bv = make_float4(0.f,0.f,0.f,0.f);
      if (nn < N) bv = *(const float4*)(Bp + (size_t)nn*ldb + k0 + lc4);
      Bs[lc4+0][lr]=bv.x; Bs[lc4+1][lr]=bv.y; Bs[lc4+2][lr]=bv.z; Bs[lc4+3][lr]=bv.w;
    } else {
      int kk = tid >> 4;        // 0..15
      int nn4 = (tid & 15)*4;   // 0..60
      float4 bv = *(const float4*)(Bp + (size_t)(k0+kk)*ldb + n0 + nn4);
      *(float4*)&Bs[kk][nn4] = bv;
    }
    __syncthreads();
    #pragma unroll
    for (int kk = 0; kk < BKK; ++kk) {
      float4 av = *(const float4*)&As[kk][ty*4];
      float4 bv = *(const float4*)&Bs[kk][tx*4];
      float a[4] = {av.x,av.y,av.z,av.w};
      float b[4] = {bv.x,bv.y,bv.z,bv.w};
      #pragma unroll
      for (int i=0;i<4;++i)
        #pragma unroll
        for (int j=0;j<4;++j)
          acc[i][j] += a[i]*b[j];
    }
    __syncthreads();
  }

  #pragma unroll
  for (int i=0;i<4;++i){
    int m = m0 + ty*4 + i;
    #pragma unroll
    for (int j=0;j<4;++j){
      int n = n0 + tx*4 + j;
      if (n >= N) continue;
      float val = acc[i][j];
      if constexpr (EPI==0) {
        C[(size_t)m*ldc + n] = val;
      } else if constexpr (EPI==1) {
        C[(size_t)m*ldc + n] = siluf_(val + ep.bias[n]);
      } else if constexpr (EPI==2) {
        float z = val + ep.bias[n];
        C[(size_t)m*ldc + n] = (z > 15.f) ? z : log1pf(__expf(z));
      } else if constexpr (EPI==3) {
        val += ep.bias[n];
        if (n < 1024) {
          ep.u_out[(size_t)m*EMBED + n] = sigmoidf_(val);
        } else if (n < 1152) {
          int jj = n - 1024;
          float z = siluf_(val);
          ep.q_out[(size_t)m*ZD + jj] = (z*ep.gamma[jj] + ep.beta2[jj]) * 0.08838834764831845f;
          ep.k_out[(size_t)m*ZD + jj] =  z*ep.gamma[128+jj] + ep.beta2[128+jj];
        } else if (n < 2176) {
          ep.r_out[(size_t)m*EMBED + (n-1152)] = siluf_(val);
        } else {
          ep.hx_out[(size_t)m*EMBED + (n-2176)] = val;
        }
      } else if constexpr (EPI==4) {
        val = (n <= m) ? val + ep.gtab[m-n] : -1e30f;
        C[(size_t)m*ldc + n] = val;
      } else if constexpr (EPI==5) {
        float z = val + ep.bias[n] + ep.hx_in[(size_t)m*EMBED+n];
        float hh = siluf_(z);
        float res = ep.resid[(size_t)m*EMBED+n];
        ep.out_p[(size_t)m*EMBED+n] = res + ep.u_in[(size_t)m*EMBED+n]*(hh-res);
      }
    }
  }
}

// ---------------------------------------------------------------- launch
extern "C" void kernel_launch(void* const* d_in, const int* in_sizes, int n_in,
                              void* d_out, int out_size, void* d_ws, size_t ws_size,
                              hipStream_t stream) {
  const float* x       = (const float*)d_in[0];
  const float* norm_w  = (const float*)d_in[1];
  const float* v_w     = (const float*)d_in[2];
  const float* v_b     = (const float*)d_in[3];
  const float* mx_w    = (const float*)d_in[4];
  const float* mx_b    = (const float*)d_in[5];
  const float* h_w     = (const float*)d_in[6];
  const float* h_b     = (const float*)d_in[7];
  const float* gamma   = (const float*)d_in[8];
  const float* beta    = (const float*)d_in[9];
  const float* alpha_rb= (const float*)d_in[10];
  const float* beta_rb = (const float*)d_in[11];
  const float* xproj_w = (const float*)d_in[12];
  const float* dt_w    = (const float*)d_in[13];
  const float* dt_b    = (const float*)d_in[14];
  const float* A_log   = (const float*)d_in[15];
  const float* D_p     = (const float*)d_in[16];
  float* out = (float*)d_out;

  float* ws = (float*)d_ws;
  size_t off = 0;
  auto alloc = [&](size_t n){ float* p = ws + off; off += n; return p; };
  const size_t BL = (size_t)BATCH*LSEQ; // 8192

  float* xn   = alloc(BL*EMBED);
  float* vbuf = alloc(BL*EMBED);
  float* xdbl = alloc(BL*XDBL_W);
  float* dtb  = alloc(BL*EMBED);
  float* mx   = alloc(BL*EMBED);
  float* ug   = alloc(BL*EMBED);
  float* qb   = alloc(BL*ZD);
  float* kb   = alloc(BL*ZD);
  float* rb   = alloc(BL*EMBED);
  float* hxb  = alloc(BL*EMBED);
  float* gtab = alloc(CHUNKC);
  float* hattn = xn;  // xn dead after scan
  float* S     = dtb; // dt dead after scan (needs 2048^2 <= BL*EMBED)

  // 1. rmsnorm
  rmsnorm_k<<<(int)BL, 256, 0, stream>>>(x, norm_w, xn);

  EpiParams ep;

  // 2. v = silu(xn @ v_w^T + v_b)
  ep = {}; ep.bias = v_b;
  gemm_k<1,true,false><<<dim3(EMBED/BN, BL/BM), 256, 0, stream>>>(
      xn, EMBED, nullptr, v_w, EMBED, vbuf, EMBED, (int)BL, EMBED, EMBED, ep);

  // 3. xdbl = xn @ xproj_w^T
  ep = {};
  gemm_k<0,true,false><<<dim3((XDBL_W+BN-1)/BN, BL/BM), 256, 0, stream>>>(
      xn, EMBED, nullptr, xproj_w, EMBED, xdbl, XDBL_W, (int)BL, XDBL_W, EMBED, ep);

  // 4. dt = softplus(xdbl[:, :64] @ dt_w^T + dt_b)
  ep = {}; ep.bias = dt_b;
  gemm_k<2,true,false><<<dim3(EMBED/BN, BL/BM), 256, 0, stream>>>(
      xdbl, XDBL_W, nullptr, dt_w, DTR, dtb, EMBED, (int)BL, EMBED, DTR, ep);

  // 5. scan -> mx = silu(ys + xn*D_p)
  scan_k<<<BATCH*(EMBED/256), 256, 0, stream>>>(xdbl, dtb, xn, A_log, D_p, mx);

  // 6. base = mx @ mx_w^T + mx_b, split epilogue
  ep = {}; ep.bias = mx_b; ep.gamma = gamma; ep.beta2 = beta;
  ep.u_out = ug; ep.q_out = qb; ep.k_out = kb; ep.r_out = rb; ep.hx_out = hxb;
  gemm_k<3,true,false><<<dim3(3200/BN, BL/BM), 256, 0, stream>>>(
      mx, EMBED, nullptr, mx_w, EMBED, nullptr, 0, (int)BL, 3200, EMBED, ep);

  // 7. rel-pos bias table
  gtab_k<<<CHUNKC/256, 256, 0, stream>>>(alpha_rb, beta_rb, gtab);

  // 8. attention per (b, chunk)
  for (int b = 0; b < BATCH; ++b) {
    for (int ch = 0; ch < LSEQ/CHUNKC; ++ch) {
      size_t ro = (size_t)b*LSEQ + (size_t)ch*CHUNKC;
      ep = {}; ep.gtab = gtab;
      gemm_k<4,true,false><<<dim3(CHUNKC/BN, CHUNKC/BM), 256, 0, stream>>>(
          qb + ro*ZD, ZD, nullptr, kb + ro*ZD, ZD, S, CHUNKC, CHUNKC, CHUNKC, ZD, ep);
      softmax_k<<<CHUNKC, 256, 0, stream>>>(S);
      ep = {};
      gemm_k<0,false,false><<<dim3(EMBED/BN, CHUNKC/BM), 256, 0, stream>>>(
          S, CHUNKC, nullptr, vbuf + ro*EMBED, EMBED, hattn + ro*EMBED, EMBED,
          CHUNKC, EMBED, CHUNKC, ep);
    }
  }

  // 9. final: h = silu(hx + (hattn*r) @ h_w^T + h_b); out = x + u*(h-x)
  ep = {}; ep.bias = h_b; ep.hx_in = hxb; ep.u_in = ug; ep.resid = x; ep.out_p = out;
  gemm_k<5,true,true><<<dim3(EMBED/BN, BL/BM), 256, 0, stream>>>(
      hattn, EMBED, rb, h_w, EMBED, nullptr, 0, (int)BL, EMBED, EMBED, ep);
}

// Round 2
// 1934.063 us; speedup vs baseline: 2.0671x; 2.0671x over previous
//
#include <hip/hip_runtime.h>
#include <hip/hip_bf16.h>
#include <math.h>

#define EMBED 1024
#define LSEQ 4096
#define BATCH 2
#define ZD 128
#define CHUNKC 2048
#define NSTATE 16
#define DTR 64
#define XDBL_W 96   // DT_RANK + 2*DSTATE
#define NSEG 64
#define TSEG 64     // LSEQ / NSEG

__device__ __forceinline__ float sigmoidf_(float x){ return 1.f/(1.f+__expf(-x)); }
__device__ __forceinline__ float siluf_(float x){ return x/(1.f+__expf(-x)); }

// ---------------------------------------------------------------- rmsnorm
__global__ __launch_bounds__(256) void rmsnorm_k(const float* __restrict__ x,
                                                 const float* __restrict__ w,
                                                 float* __restrict__ xn) {
  size_t row = blockIdx.x;
  const float* px = x + row*EMBED;
  float* po = xn + row*EMBED;
  int tid = threadIdx.x;
  float4 xv = *(const float4*)(px + tid*4);
  float ss = xv.x*xv.x + xv.y*xv.y + xv.z*xv.z + xv.w*xv.w;
  #pragma unroll
  for (int off=32; off; off>>=1) ss += __shfl_down(ss, off, 64);
  __shared__ float red[4];
  if ((tid&63)==0) red[tid>>6]=ss;
  __syncthreads();
  float tot = red[0]+red[1]+red[2]+red[3];
  float scale = rsqrtf(tot*(1.f/EMBED) + 1e-5f);
  float4 wv = *(const float4*)(w + tid*4);
  float4 o;
  o.x=xv.x*scale*wv.x; o.y=xv.y*scale*wv.y; o.z=xv.z*scale*wv.z; o.w=xv.w*scale*wv.w;
  *(float4*)(po + tid*4) = o;
}

// ---------------------------------------------------------------- gtab (Toeplitz rel-pos bias)
__global__ __launch_bounds__(256) void gtab_k(const float* __restrict__ alpha,
                                              const float* __restrict__ beta,
                                              float* __restrict__ gtab) {
  __shared__ float P[64], Q[64], F[64];
  int tid = threadIdx.x;
  if (tid < 64) {
    float a1=alpha[tid], a2=alpha[64+tid], b1=beta[tid], b2=beta[64+tid];
    P[tid]=a1*b1+a2*b2;
    Q[tid]=a2*b1-a1*b2;
    F[tid]=expf(-0.14391156831f*(float)tid); // ln(10000)/64
  }
  __syncthreads();
  int d = blockIdx.x*256 + tid;
  if (d < CHUNKC) {
    float s=0.f;
    for (int j=0;j<64;++j){
      float th = (float)d * F[j];
      float sn, cs;
      sincosf(th, &sn, &cs);
      s += P[j]*cs - Q[j]*sn;
    }
    gtab[d]=s;
  }
}

// ---------------------------------------------------------------- segment-parallel S6 scan
// pass 1 (!FINAL): per (channel, segment) compute local state h_loc (h0=0) and
//                  decay product P = prod(dA). write segP/segH [seg][2048][16].
// pass 2: sequential combine over segments -> segInit[seg][ch][n] = state BEFORE seg.
// pass 3 (FINAL): rerun segment from segInit, emit mx = silu(y + u*D).
template<bool FINAL>
__global__ __launch_bounds__(256) void seg_scan_k(
    const float* __restrict__ xdbl,
    const float* __restrict__ dtv,
    const float* __restrict__ xn,
    const float* __restrict__ A_log,
    const float* __restrict__ D_p,
    const float* __restrict__ segInit,
    float* __restrict__ segP,
    float* __restrict__ segH,
    float* __restrict__ mx)
{
  int bx = blockIdx.x;
  int seg = bx >> 3;           // 0..63
  int grp = bx & 7;            // b(1b) * dgrp(2b)
  int b = grp >> 2;
  int d = (grp & 3)*256 + threadIdx.x;
  int ch = b*EMBED + d;
  int tid = threadIdx.x;
  int tbase = seg*TSEG;

  float A[NSTATE], h[NSTATE], P[NSTATE];
  #pragma unroll
  for (int n=0;n<NSTATE;++n){
    A[n] = -__expf(A_log[(size_t)d*NSTATE+n]);
    P[n] = 1.f;
  }
  if (FINAL) {
    const float* si = segInit + ((size_t)seg*2048 + ch)*NSTATE;
    #pragma unroll
    for (int n=0;n<NSTATE;++n) h[n] = si[n];
  } else {
    #pragma unroll
    for (int n=0;n<NSTATE;++n) h[n] = 0.f;
  }
  float Dp = FINAL ? D_p[d] : 0.f;

  __shared__ float BCb[8][32];
  const float* xd  = xdbl + ((size_t)b*LSEQ + tbase)*XDBL_W + DTR;
  const float* pdt = dtv + ((size_t)b*LSEQ + tbase)*EMBED + d;
  const float* pu  = xn  + ((size_t)b*LSEQ + tbase)*EMBED + d;
  float* pmx = mx + ((size_t)b*LSEQ + tbase)*EMBED + d;

  for (int t0=0; t0<TSEG; t0+=8) {
    __syncthreads();
    { int tt = tid>>5, jj = tid&31;
      BCb[tt][jj] = xd[(size_t)(t0+tt)*XDBL_W + jj]; }
    __syncthreads();
    #pragma unroll
    for (int tt=0; tt<8; ++tt) {
      int t = t0 + tt;
      float dtt = pdt[(size_t)t*EMBED];
      float ut  = pu[(size_t)t*EMBED];
      float du = dtt*ut;
      float y = 0.f;
      #pragma unroll
      for (int n=0;n<NSTATE;++n){
        float dA = __expf(dtt*A[n]);
        h[n] = dA*h[n] + du*BCb[tt][n];
        if (!FINAL) P[n] *= dA;
        if (FINAL)  y += h[n]*BCb[tt][16+n];
      }
      if (FINAL) pmx[(size_t)t*EMBED] = siluf_(y + ut*Dp);
    }
  }
  if (!FINAL) {
    float* pp = segP + ((size_t)seg*2048 + ch)*NSTATE;
    float* ph = segH + ((size_t)seg*2048 + ch)*NSTATE;
    #pragma unroll
    for (int n=0;n<NSTATE;n+=4){
      *(float4*)(pp+n) = make_float4(P[n],P[n+1],P[n+2],P[n+3]);
      *(float4*)(ph+n) = make_float4(h[n],h[n+1],h[n+2],h[n+3]);
    }
  }
}

__global__ __launch_bounds__(256) void seg_combine_k(const float* __restrict__ segP,
                                                     const float* __restrict__ segH,
                                                     float* __restrict__ segInit) {
  int idx = blockIdx.x*256 + threadIdx.x; // 0..32767  (ch*16+n)
  float H = 0.f;
  for (int s=0; s<NSEG; ++s) {
    size_t o = (size_t)s*32768 + idx;
    float Pv = segP[o], hl = segH[o];
    segInit[o] = H;
    H = Pv*H + hl;
  }
}

// ---------------------------------------------------------------- row softmax (2048 wide)
__global__ __launch_bounds__(256) void softmax_k(float* __restrict__ S) {
  size_t row = blockIdx.x;
  float* p = S + row*CHUNKC;
  int tid = threadIdx.x;
  float v[8];
  float m = -1e30f;
  #pragma unroll
  for (int i=0;i<8;++i){ v[i]=p[tid + i*256]; m=fmaxf(m,v[i]); }
  #pragma unroll
  for (int off=32; off; off>>=1) m = fmaxf(m, __shfl_down(m, off, 64));
  __shared__ float red[4];
  if ((tid&63)==0) red[tid>>6]=m;
  __syncthreads();
  m = fmaxf(fmaxf(red[0],red[1]),fmaxf(red[2],red[3]));
  float s=0.f;
  #pragma unroll
  for (int i=0;i<8;++i){ v[i]=__expf(v[i]-m); s+=v[i]; }
  #pragma unroll
  for (int off=32; off; off>>=1) s += __shfl_down(s, off, 64);
  __syncthreads();
  if ((tid&63)==0) red[tid>>6]=s;
  __syncthreads();
  s = red[0]+red[1]+red[2]+red[3];
  float inv = 1.f/s;
  #pragma unroll
  for (int i=0;i<8;++i) p[tid + i*256] = v[i]*inv;
}

// ---------------------------------------------------------------- generic tiled GEMM
struct EpiParams {
  const float* bias;
  const float* gtab;
  const float* gamma;
  const float* beta2;
  float* u_out; float* q_out; float* k_out; float* r_out; float* hx_out;
  const float* hx_in; const float* u_in; const float* resid;
  float* out_p;
};

#define BM 64
#define BN 64
#define BKK 16

template<int EPI, bool BT, bool A2MUL>
__global__ __launch_bounds__(256) void gemm_k(
    const float* __restrict__ A, int lda, size_t sAz,
    const float* __restrict__ A2,
    const float* __restrict__ Bp, int ldb, size_t sBz,
    float* __restrict__ C, int ldc, size_t sCz,
    int M, int N, int K, EpiParams ep)
{
  A += (size_t)blockIdx.z * sAz;
  Bp += (size_t)blockIdx.z * sBz;
  if (C) C += (size_t)blockIdx.z * sCz;

  __shared__ float As[BKK][BM+4];
  __shared__ float Bs[BKK][BN+4];
  int tid = threadIdx.x;
  int m0 = blockIdx.y*BM, n0 = blockIdx.x*BN;
  float acc[4][4] = {};
  int tx = tid & 15, ty = tid >> 4;
  int lr  = tid >> 2;        // 0..63
  int lc4 = (tid & 3) * 4;   // 0,4,8,12

  for (int k0 = 0; k0 < K; k0 += BKK) {
    {
      const float* src = A + (size_t)(m0+lr)*lda + k0 + lc4;
      float4 av = *(const float4*)src;
      if constexpr (A2MUL) {
        float4 a2 = *(const float4*)(A2 + (size_t)(m0+lr)*lda + k0 + lc4);
        av.x*=a2.x; av.y*=a2.y; av.z*=a2.z; av.w*=a2.w;
      }
      As[lc4+0][lr]=av.x; As[lc4+1][lr]=av.y; As[lc4+2][lr]=av.z; As[lc4+3][lr]=av.w;
    }
    if constexpr (BT) {
      int nn = n0 + lr;
      float4 bv = make_float4(0.f,0.f,0.f,0.f);
      if (nn < N) bv = *(const float4*)(Bp + (size_t)nn*ldb + k0 + lc4);
      Bs[lc4+0][lr]=bv.x; Bs[lc4+1][lr]=bv.y; Bs[lc4+2][lr]=bv.z; Bs[lc4+3][lr]=bv.w;
    } else {
      int kk = tid >> 4;
      int nn4 = (tid & 15)*4;
      float4 bv = *(const float4*)(Bp + (size_t)(k0+kk)*ldb + n0 + nn4);
      *(float4*)&Bs[kk][nn4] = bv;
    }
    __syncthreads();
    #pragma unroll
    for (int kk = 0; kk < BKK; ++kk) {
      float4 av = *(const float4*)&As[kk][ty*4];
      float4 bv = *(const float4*)&Bs[kk][tx*4];
      float a[4] = {av.x,av.y,av.z,av.w};
      float b[4] = {bv.x,bv.y,bv.z,bv.w};
      #pragma unroll
      for (int i=0;i<4;++i)
        #pragma unroll
        for (int j=0;j<4;++j)
          acc[i][j] += a[i]*b[j];
    }
    __syncthreads();
  }

  #pragma unroll
  for (int i=0;i<4;++i){
    int m = m0 + ty*4 + i;
    #pragma unroll
    for (int j=0;j<4;++j){
      int n = n0 + tx*4 + j;
      if (n >= N) continue;
      float val = acc[i][j];
      if constexpr (EPI==0) {
        C[(size_t)m*ldc + n] = val;
      } else if constexpr (EPI==1) {
        C[(size_t)m*ldc + n] = siluf_(val + ep.bias[n]);
      } else if constexpr (EPI==2) {
        float z = val + ep.bias[n];
        C[(size_t)m*ldc + n] = (z > 15.f) ? z : log1pf(__expf(z));
      } else if constexpr (EPI==3) {
        val += ep.bias[n];
        if (n < 1024) {
          ep.u_out[(size_t)m*EMBED + n] = sigmoidf_(val);
        } else if (n < 1152) {
          int jj = n - 1024;
          float z = siluf_(val);
          ep.q_out[(size_t)m*ZD + jj] = (z*ep.gamma[jj] + ep.beta2[jj]) * 0.08838834764831845f;
          ep.k_out[(size_t)m*ZD + jj] =  z*ep.gamma[128+jj] + ep.beta2[128+jj];
        } else if (n < 2176) {
          ep.r_out[(size_t)m*EMBED + (n-1152)] = siluf_(val);
        } else {
          ep.hx_out[(size_t)m*EMBED + (n-2176)] = val;
        }
      } else if constexpr (EPI==4) {
        val = (n <= m) ? val + ep.gtab[m-n] : -1e30f;
        C[(size_t)m*ldc + n] = val;
      } else if constexpr (EPI==5) {
        float z = val + ep.bias[n] + ep.hx_in[(size_t)m*EMBED+n];
        float hh = siluf_(z);
        float res = ep.resid[(size_t)m*EMBED+n];
        ep.out_p[(size_t)m*EMBED+n] = res + ep.u_in[(size_t)m*EMBED+n]*(hh-res);
      }
    }
  }
}

// ---------------------------------------------------------------- launch
extern "C" void kernel_launch(void* const* d_in, const int* in_sizes, int n_in,
                              void* d_out, int out_size, void* d_ws, size_t ws_size,
                              hipStream_t stream) {
  const float* x       = (const float*)d_in[0];
  const float* norm_w  = (const float*)d_in[1];
  const float* v_w     = (const float*)d_in[2];
  const float* v_b     = (const float*)d_in[3];
  const float* mx_w    = (const float*)d_in[4];
  const float* mx_b    = (const float*)d_in[5];
  const float* h_w     = (const float*)d_in[6];
  const float* h_b     = (const float*)d_in[7];
  const float* gamma   = (const float*)d_in[8];
  const float* beta    = (const float*)d_in[9];
  const float* alpha_rb= (const float*)d_in[10];
  const float* beta_rb = (const float*)d_in[11];
  const float* xproj_w = (const float*)d_in[12];
  const float* dt_w    = (const float*)d_in[13];
  const float* dt_b    = (const float*)d_in[14];
  const float* A_log   = (const float*)d_in[15];
  const float* D_p     = (const float*)d_in[16];
  float* out = (float*)d_out;

  float* ws = (float*)d_ws;
  size_t off = 0;
  auto alloc = [&](size_t n){ float* p = ws + off; off += n; return p; };
  const size_t BL = (size_t)BATCH*LSEQ; // 8192

  float* xn   = alloc(BL*EMBED);
  float* vbuf = alloc(BL*EMBED);
  float* xdbl = alloc(BL*XDBL_W);
  float* dtb  = alloc(BL*EMBED);
  float* mx   = alloc(BL*EMBED);
  float* ug   = alloc(BL*EMBED);
  float* qb   = alloc(BL*ZD);
  float* kb   = alloc(BL*ZD);
  float* rb   = alloc(BL*EMBED);
  float* hxb  = alloc(BL*EMBED);
  float* gtab = alloc(CHUNKC);
  float* hattn = xn;   // xn dead after scan pass3
  float* S     = dtb;  // dtb+mx contiguous (16.78M floats) host S[4][2048][2048] after scan/base
  // segment-scan scratch aliases ug (ug written only at base GEMM, seg arrays dead by then)
  float* segP    = ug;                          // 64*2048*16 = 2.10M floats
  float* segH    = ug + (size_t)NSEG*2048*NSTATE;
  float* segInit = ug + (size_t)2*NSEG*2048*NSTATE;

  // 1. rmsnorm
  rmsnorm_k<<<(int)BL, 256, 0, stream>>>(x, norm_w, xn);

  EpiParams ep;

  // 2. v = silu(xn @ v_w^T + v_b)
  ep = {}; ep.bias = v_b;
  gemm_k<1,true,false><<<dim3(EMBED/BN, BL/BM), 256, 0, stream>>>(
      xn, EMBED, 0, nullptr, v_w, EMBED, 0, vbuf, EMBED, 0, (int)BL, EMBED, EMBED, ep);

  // 3. xdbl = xn @ xproj_w^T
  ep = {};
  gemm_k<0,true,false><<<dim3((XDBL_W+BN-1)/BN, BL/BM), 256, 0, stream>>>(
      xn, EMBED, 0, nullptr, xproj_w, EMBED, 0, xdbl, XDBL_W, 0, (int)BL, XDBL_W, EMBED, ep);

  // 4. dt = softplus(xdbl[:, :64] @ dt_w^T + dt_b)
  ep = {}; ep.bias = dt_b;
  gemm_k<2,true,false><<<dim3(EMBED/BN, BL/BM), 256, 0, stream>>>(
      xdbl, XDBL_W, 0, nullptr, dt_w, DTR, 0, dtb, EMBED, 0, (int)BL, EMBED, DTR, ep);

  // 5. segment-parallel scan -> mx = silu(ys + xn*D_p)
  seg_scan_k<false><<<NSEG*8, 256, 0, stream>>>(xdbl, dtb, xn, A_log, D_p,
                                                nullptr, segP, segH, nullptr);
  seg_combine_k<<<128, 256, 0, stream>>>(segP, segH, segInit);
  seg_scan_k<true><<<NSEG*8, 256, 0, stream>>>(xdbl, dtb, xn, A_log, D_p,
                                               segInit, nullptr, nullptr, mx);

  // 6. base = mx @ mx_w^T + mx_b, split epilogue
  ep = {}; ep.bias = mx_b; ep.gamma = gamma; ep.beta2 = beta;
  ep.u_out = ug; ep.q_out = qb; ep.k_out = kb; ep.r_out = rb; ep.hx_out = hxb;
  gemm_k<3,true,false><<<dim3(3200/BN, BL/BM), 256, 0, stream>>>(
      mx, EMBED, 0, nullptr, mx_w, EMBED, 0, nullptr, 0, 0, (int)BL, 3200, EMBED, ep);

  // 7. rel-pos bias table
  gtab_k<<<CHUNKC/256, 256, 0, stream>>>(alpha_rb, beta_rb, gtab);

  // 8. attention, all 4 (b,chunk) batched via blockIdx.z
  ep = {}; ep.gtab = gtab;
  gemm_k<4,true,false><<<dim3(CHUNKC/BN, CHUNKC/BM, 4), 256, 0, stream>>>(
      qb, ZD, (size_t)CHUNKC*ZD, nullptr, kb, ZD, (size_t)CHUNKC*ZD,
      S, CHUNKC, (size_t)CHUNKC*CHUNKC, CHUNKC, CHUNKC, ZD, ep);
  softmax_k<<<4*CHUNKC, 256, 0, stream>>>(S);
  ep = {};
  gemm_k<0,false,false><<<dim3(EMBED/BN, CHUNKC/BM, 4), 256, 0, stream>>>(
      S, CHUNKC, (size_t)CHUNKC*CHUNKC, nullptr, vbuf, EMBED, (size_t)CHUNKC*EMBED,
      hattn, EMBED, (size_t)CHUNKC*EMBED, CHUNKC, EMBED, CHUNKC, ep);

  // 9. final: h = silu(hx + (hattn*r) @ h_w^T + h_b); out = x + u*(h-x)
  ep = {}; ep.bias = h_b; ep.hx_in = hxb; ep.u_in = ug; ep.resid = x; ep.out_p = out;
  gemm_k<5,true,true><<<dim3(EMBED/BN, BL/BM), 256, 0, stream>>>(
      hattn, EMBED, 0, rb, h_w, EMBED, 0, nullptr, 0, 0, (int)BL, EMBED, EMBED, ep);
}

// Round 3
// 620.559 us; speedup vs baseline: 6.4423x; 3.1166x over previous
//
#include <hip/hip_runtime.h>
#include <hip/hip_bf16.h>
#include <math.h>

#define EMBED 1024
#define LSEQ 4096
#define BATCH 2
#define ZD 128
#define CHUNKC 2048
#define NSTATE 16
#define DTR 64
#define XDBL_W 96   // DT_RANK + 2*DSTATE
#define NSEG 64
#define TSEG 64     // LSEQ / NSEG

typedef __attribute__((ext_vector_type(8))) short bf16x8;
typedef __attribute__((ext_vector_type(4))) float f32x4;

__device__ __forceinline__ float sigmoidf_(float x){ return 1.f/(1.f+__expf(-x)); }
__device__ __forceinline__ float siluf_(float x){ return x/(1.f+__expf(-x)); }
__device__ __forceinline__ __hip_bfloat16 tobf(float x){ return __float2bfloat16(x); }
__device__ __forceinline__ float frombf(__hip_bfloat16 x){ return __bfloat162float(x); }

__device__ __forceinline__ void gload_lds16(const void* g, void* l) {
  __builtin_amdgcn_global_load_lds(
      (const __attribute__((address_space(1))) unsigned int*)g,
      (__attribute__((address_space(3))) unsigned int*)l, 16, 0, 0);
}

// ---------------------------------------------------------------- f32 -> bf16 convert
__global__ __launch_bounds__(256) void cvt_k(const float* __restrict__ s,
                                             __hip_bfloat16* __restrict__ d, int n) {
  for (int i = (blockIdx.x*256 + threadIdx.x)*4; i < n; i += gridDim.x*256*4) {
    float4 v = *(const float4*)(s + i);
    d[i+0]=tobf(v.x); d[i+1]=tobf(v.y); d[i+2]=tobf(v.z); d[i+3]=tobf(v.w);
  }
}

// ---------------------------------------------------------------- rmsnorm (dual out: f32 + bf16)
__global__ __launch_bounds__(256) void rmsnorm_k(const float* __restrict__ x,
                                                 const float* __restrict__ w,
                                                 float* __restrict__ xn,
                                                 __hip_bfloat16* __restrict__ xnb) {
  size_t row = blockIdx.x;
  const float* px = x + row*EMBED;
  int tid = threadIdx.x;
  float4 xv = *(const float4*)(px + tid*4);
  float ss = xv.x*xv.x + xv.y*xv.y + xv.z*xv.z + xv.w*xv.w;
  #pragma unroll
  for (int off=32; off; off>>=1) ss += __shfl_down(ss, off, 64);
  __shared__ float red[4];
  if ((tid&63)==0) red[tid>>6]=ss;
  __syncthreads();
  float tot = red[0]+red[1]+red[2]+red[3];
  float scale = rsqrtf(tot*(1.f/EMBED) + 1e-5f);
  float4 wv = *(const float4*)(w + tid*4);
  float4 o;
  o.x=xv.x*scale*wv.x; o.y=xv.y*scale*wv.y; o.z=xv.z*scale*wv.z; o.w=xv.w*scale*wv.w;
  *(float4*)(xn + row*EMBED + tid*4) = o;
  __hip_bfloat16* pb = xnb + row*EMBED + tid*4;
  pb[0]=tobf(o.x); pb[1]=tobf(o.y); pb[2]=tobf(o.z); pb[3]=tobf(o.w);
}

// ---------------------------------------------------------------- gtab (Toeplitz rel-pos bias)
__global__ __launch_bounds__(256) void gtab_k(const float* __restrict__ alpha,
                                              const float* __restrict__ beta,
                                              float* __restrict__ gtab) {
  __shared__ float P[64], Q[64], F[64];
  int tid = threadIdx.x;
  if (tid < 64) {
    float a1=alpha[tid], a2=alpha[64+tid], b1=beta[tid], b2=beta[64+tid];
    P[tid]=a1*b1+a2*b2;
    Q[tid]=a2*b1-a1*b2;
    F[tid]=expf(-0.14391156831f*(float)tid); // ln(10000)/64
  }
  __syncthreads();
  int d = blockIdx.x*256 + tid;
  if (d < CHUNKC) {
    float s=0.f;
    for (int j=0;j<64;++j){
      float th = (float)d * F[j];
      float sn, cs;
      sincosf(th, &sn, &cs);
      s += P[j]*cs - Q[j]*sn;
    }
    gtab[d]=s;
  }
}

// ---------------------------------------------------------------- segment-parallel S6 scan
template<bool FINAL>
__global__ __launch_bounds__(256) void seg_scan_k(
    const float* __restrict__ xdbl,
    const float* __restrict__ dtv,
    const float* __restrict__ xn,
    const float* __restrict__ A_log,
    const float* __restrict__ D_p,
    const float* __restrict__ segInit,
    float* __restrict__ segP,
    float* __restrict__ segH,
    __hip_bfloat16* __restrict__ mx)
{
  int bx = blockIdx.x;
  int seg = bx >> 3;
  int grp = bx & 7;
  int b = grp >> 2;
  int d = (grp & 3)*256 + threadIdx.x;
  int ch = b*EMBED + d;
  int tid = threadIdx.x;
  int tbase = seg*TSEG;

  float A[NSTATE], h[NSTATE], P[NSTATE];
  #pragma unroll
  for (int n=0;n<NSTATE;++n){
    A[n] = -__expf(A_log[(size_t)d*NSTATE+n]);
    P[n] = 1.f;
  }
  if (FINAL) {
    const float* si = segInit + ((size_t)seg*2048 + ch)*NSTATE;
    #pragma unroll
    for (int n=0;n<NSTATE;++n) h[n] = si[n];
  } else {
    #pragma unroll
    for (int n=0;n<NSTATE;++n) h[n] = 0.f;
  }
  float Dp = FINAL ? D_p[d] : 0.f;

  __shared__ float BCb[8][32];
  const float* xd  = xdbl + ((size_t)b*LSEQ + tbase)*XDBL_W + DTR;
  const float* pdt = dtv + ((size_t)b*LSEQ + tbase)*EMBED + d;
  const float* pu  = xn  + ((size_t)b*LSEQ + tbase)*EMBED + d;
  __hip_bfloat16* pmx = mx + ((size_t)b*LSEQ + tbase)*EMBED + d;

  for (int t0=0; t0<TSEG; t0+=8) {
    __syncthreads();
    { int tt = tid>>5, jj = tid&31;
      BCb[tt][jj] = xd[(size_t)(t0+tt)*XDBL_W + jj]; }
    __syncthreads();
    #pragma unroll
    for (int tt=0; tt<8; ++tt) {
      int t = t0 + tt;
      float dtt = pdt[(size_t)t*EMBED];
      float ut  = pu[(size_t)t*EMBED];
      float du = dtt*ut;
      float y = 0.f;
      #pragma unroll
      for (int n=0;n<NSTATE;++n){
        float dA = __expf(dtt*A[n]);
        h[n] = dA*h[n] + du*BCb[tt][n];
        if (!FINAL) P[n] *= dA;
        if (FINAL)  y += h[n]*BCb[tt][16+n];
      }
      if (FINAL) pmx[(size_t)t*EMBED] = tobf(siluf_(y + ut*Dp));
    }
  }
  if (!FINAL) {
    float* pp = segP + ((size_t)seg*2048 + ch)*NSTATE;
    float* ph = segH + ((size_t)seg*2048 + ch)*NSTATE;
    #pragma unroll
    for (int n=0;n<NSTATE;n+=4){
      *(float4*)(pp+n) = make_float4(P[n],P[n+1],P[n+2],P[n+3]);
      *(float4*)(ph+n) = make_float4(h[n],h[n+1],h[n+2],h[n+3]);
    }
  }
}

__global__ __launch_bounds__(256) void seg_combine_k(const float* __restrict__ segP,
                                                     const float* __restrict__ segH,
                                                     float* __restrict__ segInit) {
  int idx = blockIdx.x*256 + threadIdx.x;
  float H = 0.f;
  for (int s=0; s<NSEG; ++s) {
    size_t o = (size_t)s*32768 + idx;
    float Pv = segP[o], hl = segH[o];
    segInit[o] = H;
    H = Pv*H + hl;
  }
}

// ---------------------------------------------------------------- row softmax (f32 in, bf16 out)
__global__ __launch_bounds__(256) void softmax_k(const float* __restrict__ S,
                                                 __hip_bfloat16* __restrict__ Sb) {
  size_t row = blockIdx.x;
  const float* p = S + row*CHUNKC;
  __hip_bfloat16* po = Sb + row*CHUNKC;
  int tid = threadIdx.x;
  float v[8];
  float m = -1e30f;
  #pragma unroll
  for (int i=0;i<8;++i){ v[i]=p[tid + i*256]; m=fmaxf(m,v[i]); }
  #pragma unroll
  for (int off=32; off; off>>=1) m = fmaxf(m, __shfl_down(m, off, 64));
  __shared__ float red[4];
  if ((tid&63)==0) red[tid>>6]=m;
  __syncthreads();
  m = fmaxf(fmaxf(red[0],red[1]),fmaxf(red[2],red[3]));
  float s=0.f;
  #pragma unroll
  for (int i=0;i<8;++i){ v[i]=__expf(v[i]-m); s+=v[i]; }
  #pragma unroll
  for (int off=32; off; off>>=1) s += __shfl_down(s, off, 64);
  __syncthreads();
  if ((tid&63)==0) red[tid>>6]=s;
  __syncthreads();
  s = red[0]+red[1]+red[2]+red[3];
  float inv = 1.f/s;
  #pragma unroll
  for (int i=0;i<8;++i) po[tid + i*256] = tobf(v[i]*inv);
}

// ---------------------------------------------------------------- bf16 transpose V -> VT[c][n][k]
__global__ __launch_bounds__(256) void transpose_k(const unsigned short* __restrict__ vb,
                                                   unsigned short* __restrict__ VT) {
  __shared__ unsigned short t[64][68];
  int tid = threadIdx.x;
  int tr = tid>>4;          // 0..15
  int tc = (tid&15)*4;      // 0..60
  int c0 = blockIdx.x*64, r0 = blockIdx.y*64;
  #pragma unroll
  for (int it=0; it<4; ++it) {
    int r = it*16 + tr;
    ushort4 v = *(const ushort4*)(vb + (size_t)(r0+r)*EMBED + c0 + tc);
    t[r][tc+0]=v.x; t[r][tc+1]=v.y; t[r][tc+2]=v.z; t[r][tc+3]=v.w;
  }
  __syncthreads();
  int ch = r0 >> 11;
  int kb = r0 & 2047;
  #pragma unroll
  for (int it=0; it<4; ++it) {
    int nl = it*16 + tr;
    ushort4 o;
    o.x = t[tc+0][nl]; o.y = t[tc+1][nl]; o.z = t[tc+2][nl]; o.w = t[tc+3][nl];
    *(ushort4*)(VT + ((size_t)ch*EMBED + c0 + nl)*CHUNKC + kb + tc) = o;
  }
}

// ---------------------------------------------------------------- bf16 MFMA GEMM (128x128 tile, BK=64)
// C[m,n] = sum_k A[m,k]*B[n,k]  (both operands row-major, k contiguous)
// EPI: 0 silu+bias->bf16 Cb; 1 base-split; 2 QK bias+mask->f32 S; 3 PV*r->bf16; 4 final gate->f32 out
struct MEp {
  const float* bias; const float* gtab; const float* gamma; const float* beta2;
  __hip_bfloat16* ug; __hip_bfloat16* qo; __hip_bfloat16* ko; __hip_bfloat16* ro; __hip_bfloat16* hxo;
  const __hip_bfloat16* rb; const __hip_bfloat16* hxb; const __hip_bfloat16* ub;
  const float* resid; float* outp; float* Sout;
  __hip_bfloat16* Cb; int ldc;
};

#define MBM 128
#define MBK 64

template<int EPI>
__global__ __launch_bounds__(256) void mgemm_k(
    const __hip_bfloat16* __restrict__ A, int lda, long long sAz,
    const __hip_bfloat16* __restrict__ B, int ldb, long long sBz,
    int K, MEp ep)
{
  __shared__ __attribute__((aligned(16))) short As[MBM*MBK];
  __shared__ __attribute__((aligned(16))) short Bs[MBM*MBK];
  const int tid = threadIdx.x;
  const int wv = tid>>6, lane = tid&63;
  const int z = blockIdx.z;
  A += (size_t)z * sAz;
  B += (size_t)z * sBz;
  const int m0 = blockIdx.y*MBM, n0 = blockIdx.x*MBM;
  const int r8 = lane>>3, g8 = lane&7;
  const int wr = wv>>1, wc = wv&1;
  const int fr = lane&15;
  const int fo = (lane>>4)*8;

  f32x4 acc[4][4] = {};

  const __hip_bfloat16* Ag = A + (size_t)(m0 + wv*32 + r8)*lda + g8*8;
  const __hip_bfloat16* Bg = B + (size_t)(n0 + wv*32 + r8)*ldb + g8*8;
  short* Al = As + wv*32*MBK;
  short* Bl = Bs + wv*32*MBK;

  for (int k0 = 0; k0 < K; k0 += MBK) {
    __syncthreads();
    #pragma unroll
    for (int j=0;j<4;++j)
      gload_lds16(Ag + (size_t)(j*8)*lda + k0, Al + j*8*MBK);
    #pragma unroll
    for (int j=0;j<4;++j)
      gload_lds16(Bg + (size_t)(j*8)*ldb + k0, Bl + j*8*MBK);
    __syncthreads();
    #pragma unroll
    for (int kk=0; kk<2; ++kk) {
      bf16x8 af[4], bfr[4];
      #pragma unroll
      for (int mi=0;mi<4;++mi)
        af[mi] = *(const bf16x8*)&As[(wr*64 + mi*16 + fr)*MBK + kk*32 + fo];
      #pragma unroll
      for (int ni=0;ni<4;++ni)
        bfr[ni] = *(const bf16x8*)&Bs[(wc*64 + ni*16 + fr)*MBK + kk*32 + fo];
      #pragma unroll
      for (int mi=0;mi<4;++mi)
        #pragma unroll
        for (int ni=0;ni<4;++ni)
          acc[mi][ni] = __builtin_amdgcn_mfma_f32_16x16x32_bf16(af[mi], bfr[ni], acc[mi][ni], 0,0,0);
    }
  }

  const int vr = (lane>>4)*4;
  #pragma unroll
  for (int mi=0;mi<4;++mi) {
    #pragma unroll
    for (int v=0; v<4; ++v) {
      const int row = m0 + wr*64 + mi*16 + vr + v;
      #pragma unroll
      for (int ni=0;ni<4;++ni) {
        const int col = n0 + wc*64 + ni*16 + fr;
        float val = acc[mi][ni][v];
        if constexpr (EPI==0) {
          ep.Cb[(size_t)row*ep.ldc + col] = tobf(siluf_(val + ep.bias[col]));
        } else if constexpr (EPI==1) {
          val += ep.bias[col];
          if (col < 1024) {
            ep.ug[(size_t)row*EMBED + col] = tobf(sigmoidf_(val));
          } else if (col < 1152) {
            int jj = col - 1024;
            float zz = siluf_(val);
            ep.qo[(size_t)row*ZD + jj] = tobf((zz*ep.gamma[jj] + ep.beta2[jj]) * 0.08838834764831845f);
            ep.ko[(size_t)row*ZD + jj] = tobf(zz*ep.gamma[128+jj] + ep.beta2[128+jj]);
          } else if (col < 2176) {
            ep.ro[(size_t)row*EMBED + (col-1152)] = tobf(siluf_(val));
          } else {
            ep.hxo[(size_t)row*EMBED + (col-2176)] = tobf(val);
          }
        } else if constexpr (EPI==2) {
          float* Sp = ep.Sout + (size_t)z*CHUNKC*CHUNKC;
          Sp[(size_t)row*CHUNKC + col] = (col <= row) ? val + ep.gtab[row-col] : -1e30f;
        } else if constexpr (EPI==3) {
          size_t gr = (size_t)z*CHUNKC + row;
          ep.Cb[gr*EMBED + col] = tobf(val * frombf(ep.rb[gr*EMBED + col]));
        } else {
          float zz = val + ep.bias[col] + frombf(ep.hxb[(size_t)row*EMBED + col]);
          float hh = siluf_(zz);
          float res = ep.resid[(size_t)row*EMBED + col];
          ep.outp[(size_t)row*EMBED + col] = res + frombf(ep.ub[(size_t)row*EMBED + col])*(hh-res);
        }
      }
    }
  }
}

// ---------------------------------------------------------------- fp32 tiled GEMM (small ops only)
struct EpiParams { const float* bias; };

#define BM 64
#define BN 64
#define BKK 16

template<int EPI>
__global__ __launch_bounds__(256) void gemm_k(
    const float* __restrict__ A, int lda,
    const float* __restrict__ Bp, int ldb,
    float* __restrict__ C, int ldc,
    int M, int N, int K, EpiParams ep)
{
  __shared__ float As[BKK][BM+4];
  __shared__ float Bs[BKK][BN+4];
  int tid = threadIdx.x;
  int m0 = blockIdx.y*BM, n0 = blockIdx.x*BN;
  float acc[4][4] = {};
  int tx = tid & 15, ty = tid >> 4;
  int lr  = tid >> 2;
  int lc4 = (tid & 3) * 4;

  for (int k0 = 0; k0 < K; k0 += BKK) {
    {
      const float* src = A + (size_t)(m0+lr)*lda + k0 + lc4;
      float4 av = *(const float4*)src;
      As[lc4+0][lr]=av.x; As[lc4+1][lr]=av.y; As[lc4+2][lr]=av.z; As[lc4+3][lr]=av.w;
    }
    {
      int nn = n0 + lr;
      float4 bv = make_float4(0.f,0.f,0.f,0.f);
      if (nn < N) bv = *(const float4*)(Bp + (size_t)nn*ldb + k0 + lc4);
      Bs[lc4+0][lr]=bv.x; Bs[lc4+1][lr]=bv.y; Bs[lc4+2][lr]=bv.z; Bs[lc4+3][lr]=bv.w;
    }
    __syncthreads();
    #pragma unroll
    for (int kk = 0; kk < BKK; ++kk) {
      float4 av = *(const float4*)&As[kk][ty*4];
      float4 bv = *(const float4*)&Bs[kk][tx*4];
      float a[4] = {av.x,av.y,av.z,av.w};
      float b[4] = {bv.x,bv.y,bv.z,bv.w};
      #pragma unroll
      for (int i=0;i<4;++i)
        #pragma unroll
        for (int j=0;j<4;++j)
          acc[i][j] += a[i]*b[j];
    }
    __syncthreads();
  }

  #pragma unroll
  for (int i=0;i<4;++i){
    int m = m0 + ty*4 + i;
    #pragma unroll
    for (int j=0;j<4;++j){
      int n = n0 + tx*4 + j;
      if (n >= N) continue;
      float val = acc[i][j];
      if constexpr (EPI==0) {
        C[(size_t)m*ldc + n] = val;
      } else {
        float zv = val + ep.bias[n];
        C[(size_t)m*ldc + n] = (zv > 15.f) ? zv : log1pf(__expf(zv));
      }
    }
  }
}

// ---------------------------------------------------------------- launch
extern "C" void kernel_launch(void* const* d_in, const int* in_sizes, int n_in,
                              void* d_out, int out_size, void* d_ws, size_t ws_size,
                              hipStream_t stream) {
  const float* x       = (const float*)d_in[0];
  const float* norm_w  = (const float*)d_in[1];
  const float* v_w     = (const float*)d_in[2];
  const float* v_b     = (const float*)d_in[3];
  const float* mx_w    = (const float*)d_in[4];
  const float* mx_b    = (const float*)d_in[5];
  const float* h_w     = (const float*)d_in[6];
  const float* h_b     = (const float*)d_in[7];
  const float* gamma   = (const float*)d_in[8];
  const float* beta    = (const float*)d_in[9];
  const float* alpha_rb= (const float*)d_in[10];
  const float* beta_rb = (const float*)d_in[11];
  const float* xproj_w = (const float*)d_in[12];
  const float* dt_w    = (const float*)d_in[13];
  const float* dt_b    = (const float*)d_in[14];
  const float* A_log   = (const float*)d_in[15];
  const float* D_p     = (const float*)d_in[16];
  float* out = (float*)d_out;

  float* ws = (float*)d_ws;
  size_t off = 0;
  auto alloc = [&](size_t n){ float* p = ws + off; off += n; return p; };
  const size_t BL = (size_t)BATCH*LSEQ; // 8192

  float* xn      = alloc(BL*EMBED);        // f32; later aliased by Sb (bf16 4*2048*2048)
  float* scratch = alloc((size_t)2*CHUNKC*CHUNKC*2); // 16.78M f32: dtb, seg*, then S
  float* xdbl    = alloc(BL*XDBL_W);
  float* gtab    = alloc(CHUNKC);
  auto balloc = [&](size_t nbf){ __hip_bfloat16* p = (__hip_bfloat16*)(ws + off); off += (nbf+1)/2; return p; };
  __hip_bfloat16* xnb   = balloc(BL*EMBED);   // later reused as VT
  __hip_bfloat16* vbufb = balloc(BL*EMBED);
  __hip_bfloat16* mxb   = balloc(BL*EMBED);
  __hip_bfloat16* qb    = balloc(BL*ZD);
  __hip_bfloat16* kb    = balloc(BL*ZD);
  __hip_bfloat16* ugb   = balloc(BL*EMBED);
  __hip_bfloat16* rbb   = balloc(BL*EMBED);
  __hip_bfloat16* hxbb  = balloc(BL*EMBED);
  __hip_bfloat16* hrb   = balloc(BL*EMBED);
  __hip_bfloat16* vwb   = balloc((size_t)EMBED*EMBED);
  __hip_bfloat16* mxwb  = balloc((size_t)3200*EMBED);
  __hip_bfloat16* hwb   = balloc((size_t)EMBED*EMBED);

  float* dtb = scratch;
  float* segP    = scratch + BL*EMBED;
  float* segH    = segP + (size_t)NSEG*2048*NSTATE;
  float* segInit = segH + (size_t)NSEG*2048*NSTATE;
  float* S  = scratch;                      // after scan
  __hip_bfloat16* Sb = (__hip_bfloat16*)xn; // after scan
  __hip_bfloat16* VT = xnb;                 // after v GEMM

  // 0. weight conversions
  cvt_k<<<512, 256, 0, stream>>>(v_w,  vwb,  EMBED*EMBED);
  cvt_k<<<512, 256, 0, stream>>>(mx_w, mxwb, 3200*EMBED);
  cvt_k<<<512, 256, 0, stream>>>(h_w,  hwb,  EMBED*EMBED);
  gtab_k<<<CHUNKC/256, 256, 0, stream>>>(alpha_rb, beta_rb, gtab);

  // 1. rmsnorm
  rmsnorm_k<<<(int)BL, 256, 0, stream>>>(x, norm_w, xn, xnb);

  MEp ep;

  // 2. v = silu(xn @ v_w^T + v_b)  [bf16 out]
  ep = {}; ep.bias = v_b; ep.Cb = vbufb; ep.ldc = EMBED;
  mgemm_k<0><<<dim3(EMBED/MBM, BL/MBM), 256, 0, stream>>>(
      xnb, EMBED, 0, vwb, EMBED, 0, EMBED, ep);

  // 2b. transpose V per chunk
  transpose_k<<<dim3(EMBED/64, BL/64), 256, 0, stream>>>(
      (const unsigned short*)vbufb, (unsigned short*)VT);

  // 3. xdbl = xn @ xproj_w^T  (f32)
  { EpiParams fep{};
    gemm_k<0><<<dim3((XDBL_W+BN-1)/BN, BL/BM), 256, 0, stream>>>(
        xn, EMBED, xproj_w, EMBED, xdbl, XDBL_W, (int)BL, XDBL_W, EMBED, fep); }

  // 4. dt = softplus(xdbl[:, :64] @ dt_w^T + dt_b)  (f32)
  { EpiParams fep{dt_b};
    gemm_k<1><<<dim3(EMBED/BN, BL/BM), 256, 0, stream>>>(
        xdbl, XDBL_W, dt_w, DTR, dtb, EMBED, (int)BL, EMBED, DTR, fep); }

  // 5. segment-parallel scan -> mxb = bf16(silu(ys + u*D))
  seg_scan_k<false><<<NSEG*8, 256, 0, stream>>>(xdbl, dtb, xn, A_log, D_p,
                                                nullptr, segP, segH, nullptr);
  seg_combine_k<<<128, 256, 0, stream>>>(segP, segH, segInit);
  seg_scan_k<true><<<NSEG*8, 256, 0, stream>>>(xdbl, dtb, xn, A_log, D_p,
                                               segInit, nullptr, nullptr, mxb);

  // 6. base = mx @ mx_w^T + mx_b, split epilogue (bf16 outs)
  ep = {}; ep.bias = mx_b; ep.gamma = gamma; ep.beta2 = beta;
  ep.ug = ugb; ep.qo = qb; ep.ko = kb; ep.ro = rbb; ep.hxo = hxbb;
  mgemm_k<1><<<dim3(3200/MBM, BL/MBM), 256, 0, stream>>>(
      mxb, EMBED, 0, mxwb, EMBED, 0, EMBED, ep);

  // 7. QK^T + bias + mask -> f32 S
  ep = {}; ep.gtab = gtab; ep.Sout = S;
  mgemm_k<2><<<dim3(CHUNKC/MBM, CHUNKC/MBM, 4), 256, 0, stream>>>(
      qb, ZD, (long long)CHUNKC*ZD, kb, ZD, (long long)CHUNKC*ZD, ZD, ep);

  // 8. softmax (f32 -> bf16)
  softmax_k<<<4*CHUNKC, 256, 0, stream>>>(S, Sb);

  // 9. P@V, fused *r -> bf16 hrb
  ep = {}; ep.rb = rbb; ep.Cb = hrb;
  mgemm_k<3><<<dim3(EMBED/MBM, CHUNKC/MBM, 4), 256, 0, stream>>>(
      Sb, CHUNKC, (long long)CHUNKC*CHUNKC, VT, CHUNKC, (long long)EMBED*CHUNKC, CHUNKC, ep);

  // 10. final: h = silu(hx + (h*r) @ h_w^T + h_b); out = x + u*(h-x)
  ep = {}; ep.bias = h_b; ep.hxb = hxbb; ep.ub = ugb; ep.resid = x; ep.outp = out;
  mgemm_k<4><<<dim3(EMBED/MBM, BL/MBM), 256, 0, stream>>>(
      hrb, EMBED, 0, hwb, EMBED, 0, EMBED, ep);
}

// Round 4
// 518.229 us; speedup vs baseline: 7.7145x; 1.1975x over previous
//
#include <hip/hip_runtime.h>
#include <hip/hip_bf16.h>
#include <math.h>

#define EMBED 1024
#define LSEQ 4096
#define BATCH 2
#define ZD 128
#define CHUNKC 2048
#define NSTATE 16
#define DTR 64
#define XDBL_W 96   // DT_RANK + 2*DSTATE
#define NSEG 64
#define TSEG 64     // LSEQ / NSEG

typedef __attribute__((ext_vector_type(8))) short bf16x8;
typedef __attribute__((ext_vector_type(4))) float f32x4;

__device__ __forceinline__ float sigmoidf_(float x){ return 1.f/(1.f+__expf(-x)); }
__device__ __forceinline__ float siluf_(float x){ return x/(1.f+__expf(-x)); }
__device__ __forceinline__ __hip_bfloat16 tobf(float x){ return __float2bfloat16(x); }
__device__ __forceinline__ float frombf(__hip_bfloat16 x){ return __bfloat162float(x); }

__device__ __forceinline__ void gload_lds16(const void* g, void* l) {
  __builtin_amdgcn_global_load_lds(
      (const __attribute__((address_space(1))) unsigned int*)g,
      (__attribute__((address_space(3))) unsigned int*)l, 16, 0, 0);
}

// ---------------------------------------------------------------- f32 -> bf16 convert
__global__ __launch_bounds__(256) void cvt_k(const float* __restrict__ s,
                                             __hip_bfloat16* __restrict__ d, int n) {
  for (int i = (blockIdx.x*256 + threadIdx.x)*4; i < n; i += gridDim.x*256*4) {
    float4 v = *(const float4*)(s + i);
    d[i+0]=tobf(v.x); d[i+1]=tobf(v.y); d[i+2]=tobf(v.z); d[i+3]=tobf(v.w);
  }
}

// zero-padded convert (rows >= srcRows -> 0)
__global__ __launch_bounds__(256) void cvt_pad_k(const float* __restrict__ s,
                                                 __hip_bfloat16* __restrict__ d,
                                                 int srcRows, int cols, int dstRows) {
  int idx = blockIdx.x*256 + threadIdx.x;
  if (idx >= dstRows*cols) return;
  int r = idx / cols;
  d[idx] = tobf(r < srcRows ? s[idx] : 0.f);
}

// ---------------------------------------------------------------- rmsnorm (dual out: f32 + bf16)
__global__ __launch_bounds__(256) void rmsnorm_k(const float* __restrict__ x,
                                                 const float* __restrict__ w,
                                                 float* __restrict__ xn,
                                                 __hip_bfloat16* __restrict__ xnb) {
  size_t row = blockIdx.x;
  const float* px = x + row*EMBED;
  int tid = threadIdx.x;
  float4 xv = *(const float4*)(px + tid*4);
  float ss = xv.x*xv.x + xv.y*xv.y + xv.z*xv.z + xv.w*xv.w;
  #pragma unroll
  for (int off=32; off; off>>=1) ss += __shfl_down(ss, off, 64);
  __shared__ float red[4];
  if ((tid&63)==0) red[tid>>6]=ss;
  __syncthreads();
  float tot = red[0]+red[1]+red[2]+red[3];
  float scale = rsqrtf(tot*(1.f/EMBED) + 1e-5f);
  float4 wv = *(const float4*)(w + tid*4);
  float4 o;
  o.x=xv.x*scale*wv.x; o.y=xv.y*scale*wv.y; o.z=xv.z*scale*wv.z; o.w=xv.w*scale*wv.w;
  *(float4*)(xn + row*EMBED + tid*4) = o;
  __hip_bfloat16* pb = xnb + row*EMBED + tid*4;
  pb[0]=tobf(o.x); pb[1]=tobf(o.y); pb[2]=tobf(o.z); pb[3]=tobf(o.w);
}

// ---------------------------------------------------------------- gtab (Toeplitz rel-pos bias)
__global__ __launch_bounds__(256) void gtab_k(const float* __restrict__ alpha,
                                              const float* __restrict__ beta,
                                              float* __restrict__ gtab) {
  __shared__ float P[64], Q[64], F[64];
  int tid = threadIdx.x;
  if (tid < 64) {
    float a1=alpha[tid], a2=alpha[64+tid], b1=beta[tid], b2=beta[64+tid];
    P[tid]=a1*b1+a2*b2;
    Q[tid]=a2*b1-a1*b2;
    F[tid]=expf(-0.14391156831f*(float)tid); // ln(10000)/64
  }
  __syncthreads();
  int d = blockIdx.x*256 + tid;
  if (d < CHUNKC) {
    float s=0.f;
    for (int j=0;j<64;++j){
      float th = (float)d * F[j];
      float sn, cs;
      sincosf(th, &sn, &cs);
      s += P[j]*cs - Q[j]*sn;
    }
    gtab[d]=s;
  }
}

// ---------------------------------------------------------------- segment-parallel S6 scan
template<bool FINAL>
__global__ __launch_bounds__(256) void seg_scan_k(
    const float* __restrict__ xdbl,
    const float* __restrict__ dtv,
    const float* __restrict__ xn,
    const float* __restrict__ A_log,
    const float* __restrict__ D_p,
    const float* __restrict__ segInit,
    float* __restrict__ segP,
    float* __restrict__ segH,
    __hip_bfloat16* __restrict__ mx)
{
  int bx = blockIdx.x;
  int seg = bx >> 3;
  int grp = bx & 7;
  int b = grp >> 2;
  int d = (grp & 3)*256 + threadIdx.x;
  int ch = b*EMBED + d;
  int tid = threadIdx.x;
  int tbase = seg*TSEG;

  float A[NSTATE], h[NSTATE], P[NSTATE];
  #pragma unroll
  for (int n=0;n<NSTATE;++n){
    A[n] = -__expf(A_log[(size_t)d*NSTATE+n]);
    P[n] = 1.f;
  }
  if (FINAL) {
    const float* si = segInit + ((size_t)seg*2048 + ch)*NSTATE;
    #pragma unroll
    for (int n=0;n<NSTATE;++n) h[n] = si[n];
  } else {
    #pragma unroll
    for (int n=0;n<NSTATE;++n) h[n] = 0.f;
  }
  float Dp = FINAL ? D_p[d] : 0.f;

  __shared__ float BCb[8][32];
  const float* xd  = xdbl + ((size_t)b*LSEQ + tbase)*XDBL_W + DTR;
  const float* pdt = dtv + ((size_t)b*LSEQ + tbase)*EMBED + d;
  const float* pu  = xn  + ((size_t)b*LSEQ + tbase)*EMBED + d;
  __hip_bfloat16* pmx = mx + ((size_t)b*LSEQ + tbase)*EMBED + d;

  for (int t0=0; t0<TSEG; t0+=8) {
    __syncthreads();
    { int tt = tid>>5, jj = tid&31;
      BCb[tt][jj] = xd[(size_t)(t0+tt)*XDBL_W + jj]; }
    __syncthreads();
    #pragma unroll
    for (int tt=0; tt<8; ++tt) {
      int t = t0 + tt;
      float dtt = pdt[(size_t)t*EMBED];
      float ut  = pu[(size_t)t*EMBED];
      float du = dtt*ut;
      float y = 0.f;
      #pragma unroll
      for (int n=0;n<NSTATE;++n){
        float dA = __expf(dtt*A[n]);
        h[n] = dA*h[n] + du*BCb[tt][n];
        if (!FINAL) P[n] *= dA;
        if (FINAL)  y += h[n]*BCb[tt][16+n];
      }
      if (FINAL) pmx[(size_t)t*EMBED] = tobf(siluf_(y + ut*Dp));
    }
  }
  if (!FINAL) {
    float* pp = segP + ((size_t)seg*2048 + ch)*NSTATE;
    float* ph = segH + ((size_t)seg*2048 + ch)*NSTATE;
    #pragma unroll
    for (int n=0;n<NSTATE;n+=4){
      *(float4*)(pp+n) = make_float4(P[n],P[n+1],P[n+2],P[n+3]);
      *(float4*)(ph+n) = make_float4(h[n],h[n+1],h[n+2],h[n+3]);
    }
  }
}

__global__ __launch_bounds__(256) void seg_combine_k(const float* __restrict__ segP,
                                                     const float* __restrict__ segH,
                                                     float* __restrict__ segInit) {
  int idx = blockIdx.x*256 + threadIdx.x;
  float H = 0.f;
  for (int s=0; s<NSEG; ++s) {
    size_t o = (size_t)s*32768 + idx;
    float Pv = segP[o], hl = segH[o];
    segInit[o] = H;
    H = Pv*H + hl;
  }
}

// ---------------------------------------------------------------- row softmax (f32 in, bf16 out), causal-aware
__global__ __launch_bounds__(256) void softmax_k(const float* __restrict__ S,
                                                 __hip_bfloat16* __restrict__ Sb) {
  size_t row = blockIdx.x;
  const float* p = S + row*CHUNKC;
  __hip_bfloat16* po = Sb + row*CHUNKC;
  int tid = threadIdx.x;
  int r = (int)(row & (CHUNKC-1));
  int nb = (r >> 8) + 1;             // 256-wide column blocks that contain valid cols
  float v[8];
  float m = -1e30f;
  #pragma unroll
  for (int i=0;i<8;++i){
    if (i < nb) {
      float t = p[tid + i*256];
      v[i] = (i*256 + tid <= r) ? t : -1e30f;
    } else v[i] = -1e30f;
    m = fmaxf(m, v[i]);
  }
  #pragma unroll
  for (int off=32; off; off>>=1) m = fmaxf(m, __shfl_down(m, off, 64));
  __shared__ float red[4];
  if ((tid&63)==0) red[tid>>6]=m;
  __syncthreads();
  m = fmaxf(fmaxf(red[0],red[1]),fmaxf(red[2],red[3]));
  float s=0.f;
  #pragma unroll
  for (int i=0;i<8;++i){ v[i]=__expf(v[i]-m); s+=v[i]; }
  #pragma unroll
  for (int off=32; off; off>>=1) s += __shfl_down(s, off, 64);
  __syncthreads();
  if ((tid&63)==0) red[tid>>6]=s;
  __syncthreads();
  s = red[0]+red[1]+red[2]+red[3];
  float inv = 1.f/s;
  #pragma unroll
  for (int i=0;i<8;++i) po[tid + i*256] = tobf(v[i]*inv);
}

// ---------------------------------------------------------------- bf16 transpose V -> VT[c][n][k]
__global__ __launch_bounds__(256) void transpose_k(const unsigned short* __restrict__ vb,
                                                   unsigned short* __restrict__ VT) {
  __shared__ unsigned short t[64][68];
  int tid = threadIdx.x;
  int tr = tid>>4;          // 0..15
  int tc = (tid&15)*4;      // 0..60
  int c0 = blockIdx.x*64, r0 = blockIdx.y*64;
  #pragma unroll
  for (int it=0; it<4; ++it) {
    int r = it*16 + tr;
    ushort4 v = *(const ushort4*)(vb + (size_t)(r0+r)*EMBED + c0 + tc);
    t[r][tc+0]=v.x; t[r][tc+1]=v.y; t[r][tc+2]=v.z; t[r][tc+3]=v.w;
  }
  __syncthreads();
  int ch = r0 >> 11;
  int kb = r0 & 2047;
  #pragma unroll
  for (int it=0; it<4; ++it) {
    int nl = it*16 + tr;
    ushort4 o;
    o.x = t[tc+0][nl]; o.y = t[tc+1][nl]; o.z = t[tc+2][nl]; o.w = t[tc+3][nl];
    *(ushort4*)(VT + ((size_t)ch*EMBED + c0 + nl)*CHUNKC + kb + tc) = o;
  }
}

// ---------------------------------------------------------------- bf16 MFMA GEMM
// 128x128 tile, BK=64, 2-phase double-buffered LDS, XOR-swizzled staging/reads.
// C[m,n] = sum_k A[m,k]*B[n,k] (both row-major, k contiguous)
// EPI: 0 silu+bias->bf16; 1 base-split; 2 QK bias+mask->f32 (upper tiles skipped);
//      3 PV*r->bf16 (TRIK: K clipped to m0+128); 4 final gate->f32 out;
//      5 xdbl dual (f32 96 + bf16 64); 6 dt softplus->f32
struct MEp {
  const float* bias; const float* gtab; const float* gamma; const float* beta2;
  __hip_bfloat16* ug; __hip_bfloat16* qo; __hip_bfloat16* ko; __hip_bfloat16* ro; __hip_bfloat16* hxo;
  const __hip_bfloat16* rb; const __hip_bfloat16* hxb; const __hip_bfloat16* ub;
  const float* resid; float* outp; float* Sout;
  __hip_bfloat16* Cb; int ldc;
  float* f32o; __hip_bfloat16* bf16o;
};

#define MBM 128
#define MBK 64

template<int EPI, bool TRIK>
__global__ __launch_bounds__(256) void mgemm_k(
    const __hip_bfloat16* __restrict__ A, int lda, long long sAz,
    const __hip_bfloat16* __restrict__ B, int ldb, long long sBz,
    int K, MEp ep)
{
  __shared__ __attribute__((aligned(16))) short As[2][MBM*MBK];
  __shared__ __attribute__((aligned(16))) short Bs[2][MBM*MBK];
  const int tid = threadIdx.x;
  const int wv = tid>>6, lane = tid&63;
  const int z = blockIdx.z;
  A += (size_t)z * sAz;
  B += (size_t)z * sBz;
  const int m0 = blockIdx.y*MBM, n0 = blockIdx.x*MBM;
  if constexpr (EPI==2) { if (n0 > m0 + (MBM-1)) return; }  // fully-masked tile
  const int r8 = lane>>3, g8 = lane&7;
  const int csrc = g8 ^ r8;               // inverse-swizzled source chunk
  const int wr = wv>>1, wc = wv&1;
  const int fr = lane&15, q = lane>>4;
  const int x7 = fr & 7;

  int Ktot = K;
  if constexpr (TRIK) { int km = m0 + MBM; Ktot = km < K ? km : K; }
  const int nt = Ktot / MBK;

  f32x4 acc[4][4] = {};

  const __hip_bfloat16* Ag = A + (size_t)(m0 + wv*32 + r8)*lda + csrc*8;
  const __hip_bfloat16* Bg = B + (size_t)(n0 + wv*32 + r8)*ldb + csrc*8;

  auto stage = [&](int buf, int k0){
    short* Al = &As[buf][wv*32*MBK];
    short* Bl = &Bs[buf][wv*32*MBK];
    #pragma unroll
    for (int j=0;j<4;++j)
      gload_lds16(Ag + (size_t)(j*8)*lda + k0, Al + j*8*MBK);
    #pragma unroll
    for (int j=0;j<4;++j)
      gload_lds16(Bg + (size_t)(j*8)*ldb + k0, Bl + j*8*MBK);
  };

  stage(0, 0);
  __syncthreads();          // drains vmcnt(0) — buf0 ready

  int cur = 0;
  for (int t=0; t<nt; ++t) {
    if (t+1 < nt) stage(cur^1, (t+1)*MBK);   // prefetch next tile (in flight during compute)
    const short* Ab = &As[cur][0];
    const short* Bb = &Bs[cur][0];
    #pragma unroll
    for (int kk=0; kk<2; ++kk) {
      const int pos8 = ((kk*4 + q) ^ x7) * 8;   // swizzled 16B-chunk within row
      bf16x8 af[4], bfr[4];
      #pragma unroll
      for (int mi=0;mi<4;++mi)
        af[mi] = *(const bf16x8*)&Ab[(wr*64 + mi*16 + fr)*MBK + pos8];
      #pragma unroll
      for (int ni=0;ni<4;++ni)
        bfr[ni] = *(const bf16x8*)&Bb[(wc*64 + ni*16 + fr)*MBK + pos8];
      #pragma unroll
      for (int mi=0;mi<4;++mi)
        #pragma unroll
        for (int ni=0;ni<4;++ni)
          acc[mi][ni] = __builtin_amdgcn_mfma_f32_16x16x32_bf16(af[mi], bfr[ni], acc[mi][ni], 0,0,0);
    }
    __syncthreads();        // drains this iter's prefetch + all LDS reads
    cur ^= 1;
  }

  const int vr = (lane>>4)*4;
  #pragma unroll
  for (int mi=0;mi<4;++mi) {
    #pragma unroll
    for (int v=0; v<4; ++v) {
      const int row = m0 + wr*64 + mi*16 + vr + v;
      #pragma unroll
      for (int ni=0;ni<4;++ni) {
        const int col = n0 + wc*64 + ni*16 + fr;
        float val = acc[mi][ni][v];
        if constexpr (EPI==0) {
          ep.Cb[(size_t)row*ep.ldc + col] = tobf(siluf_(val + ep.bias[col]));
        } else if constexpr (EPI==1) {
          val += ep.bias[col];
          if (col < 1024) {
            ep.ug[(size_t)row*EMBED + col] = tobf(sigmoidf_(val));
          } else if (col < 1152) {
            int jj = col - 1024;
            float zz = siluf_(val);
            ep.qo[(size_t)row*ZD + jj] = tobf((zz*ep.gamma[jj] + ep.beta2[jj]) * 0.08838834764831845f);
            ep.ko[(size_t)row*ZD + jj] = tobf(zz*ep.gamma[128+jj] + ep.beta2[128+jj]);
          } else if (col < 2176) {
            ep.ro[(size_t)row*EMBED + (col-1152)] = tobf(siluf_(val));
          } else {
            ep.hxo[(size_t)row*EMBED + (col-2176)] = tobf(val);
          }
        } else if constexpr (EPI==2) {
          float* Sp = ep.Sout + (size_t)z*CHUNKC*CHUNKC;
          Sp[(size_t)row*CHUNKC + col] = (col <= row) ? val + ep.gtab[row-col] : -1e30f;
        } else if constexpr (EPI==3) {
          size_t gr = (size_t)z*CHUNKC + row;
          ep.Cb[gr*EMBED + col] = tobf(val * frombf(ep.rb[gr*EMBED + col]));
        } else if constexpr (EPI==4) {
          float zz = val + ep.bias[col] + frombf(ep.hxb[(size_t)row*EMBED + col]);
          float hh = siluf_(zz);
          float res = ep.resid[(size_t)row*EMBED + col];
          ep.outp[(size_t)row*EMBED + col] = res + frombf(ep.ub[(size_t)row*EMBED + col])*(hh-res);
        } else if constexpr (EPI==5) {
          if (col < XDBL_W) ep.f32o[(size_t)row*XDBL_W + col] = val;
          if (col < DTR)    ep.bf16o[(size_t)row*DTR + col] = tobf(val);
        } else {
          float zv = val + ep.bias[col];
          ep.f32o[(size_t)row*EMBED + col] = (zv > 15.f) ? zv : log1pf(__expf(zv));
        }
      }
    }
  }
}

// ---------------------------------------------------------------- launch
extern "C" void kernel_launch(void* const* d_in, const int* in_sizes, int n_in,
                              void* d_out, int out_size, void* d_ws, size_t ws_size,
                              hipStream_t stream) {
  const float* x       = (const float*)d_in[0];
  const float* norm_w  = (const float*)d_in[1];
  const float* v_w     = (const float*)d_in[2];
  const float* v_b     = (const float*)d_in[3];
  const float* mx_w    = (const float*)d_in[4];
  const float* mx_b    = (const float*)d_in[5];
  const float* h_w     = (const float*)d_in[6];
  const float* h_b     = (const float*)d_in[7];
  const float* gamma   = (const float*)d_in[8];
  const float* beta    = (const float*)d_in[9];
  const float* alpha_rb= (const float*)d_in[10];
  const float* beta_rb = (const float*)d_in[11];
  const float* xproj_w = (const float*)d_in[12];
  const float* dt_w    = (const float*)d_in[13];
  const float* dt_b    = (const float*)d_in[14];
  const float* A_log   = (const float*)d_in[15];
  const float* D_p     = (const float*)d_in[16];
  float* out = (float*)d_out;

  float* ws = (float*)d_ws;
  size_t off = 0;
  auto alloc = [&](size_t n){ float* p = ws + off; off += n; return p; };
  const size_t BL = (size_t)BATCH*LSEQ; // 8192

  float* xn      = alloc(BL*EMBED);        // f32; later aliased by Sb
  float* scratch = alloc((size_t)2*CHUNKC*CHUNKC*2); // 16.78M f32: dtb+seg*, then S
  float* xdbl    = alloc(BL*XDBL_W);
  float* gtab    = alloc(CHUNKC);
  auto balloc = [&](size_t nbf){ __hip_bfloat16* p = (__hip_bfloat16*)(ws + off); off += (nbf+1)/2; return p; };
  __hip_bfloat16* xnb   = balloc(BL*EMBED);   // later reused as VT
  __hip_bfloat16* vbufb = balloc(BL*EMBED);
  __hip_bfloat16* mxb   = balloc(BL*EMBED);
  __hip_bfloat16* qb    = balloc(BL*ZD);
  __hip_bfloat16* kb    = balloc(BL*ZD);
  __hip_bfloat16* ugb   = balloc(BL*EMBED);
  __hip_bfloat16* rbb   = balloc(BL*EMBED);
  __hip_bfloat16* hxbb  = balloc(BL*EMBED);
  __hip_bfloat16* hrb   = balloc(BL*EMBED);
  __hip_bfloat16* xdblb = balloc(BL*DTR);
  __hip_bfloat16* vwb   = balloc((size_t)EMBED*EMBED);
  __hip_bfloat16* mxwb  = balloc((size_t)3200*EMBED);
  __hip_bfloat16* hwb   = balloc((size_t)EMBED*EMBED);
  __hip_bfloat16* xpwb  = balloc((size_t)128*EMBED);   // xproj_w padded 96->128 rows
  __hip_bfloat16* dtwb  = balloc((size_t)EMBED*DTR);

  float* dtb     = scratch;
  float* segP    = scratch + BL*EMBED;
  float* segH    = segP + (size_t)NSEG*2048*NSTATE;
  float* segInit = segH + (size_t)NSEG*2048*NSTATE;
  float* S  = scratch;                      // after scan
  __hip_bfloat16* Sb = (__hip_bfloat16*)xn; // after scan
  __hip_bfloat16* VT = xnb;                 // after v + xdbl GEMMs

  // 0. weight conversions + bias table
  cvt_k<<<512, 256, 0, stream>>>(v_w,  vwb,  EMBED*EMBED);
  cvt_k<<<512, 256, 0, stream>>>(mx_w, mxwb, 3200*EMBED);
  cvt_k<<<512, 256, 0, stream>>>(h_w,  hwb,  EMBED*EMBED);
  cvt_k<<<64,  256, 0, stream>>>(dt_w, dtwb, EMBED*DTR);
  cvt_pad_k<<<(128*EMBED+255)/256, 256, 0, stream>>>(xproj_w, xpwb, XDBL_W, EMBED, 128);
  gtab_k<<<CHUNKC/256, 256, 0, stream>>>(alpha_rb, beta_rb, gtab);

  // 1. rmsnorm
  rmsnorm_k<<<(int)BL, 256, 0, stream>>>(x, norm_w, xn, xnb);

  MEp ep;

  // 2. v = silu(xn @ v_w^T + v_b)  [bf16]
  ep = {}; ep.bias = v_b; ep.Cb = vbufb; ep.ldc = EMBED;
  mgemm_k<0,false><<<dim3(EMBED/MBM, BL/MBM), 256, 0, stream>>>(
      xnb, EMBED, 0, vwb, EMBED, 0, EMBED, ep);

  // 3. xdbl = xn @ xproj_w^T  (f32 96 cols + bf16 first 64)
  ep = {}; ep.f32o = xdbl; ep.bf16o = xdblb;
  mgemm_k<5,false><<<dim3(1, BL/MBM), 256, 0, stream>>>(
      xnb, EMBED, 0, xpwb, EMBED, 0, EMBED, ep);

  // 4. dt = softplus(xdbl[:, :64] @ dt_w^T + dt_b)  (f32)
  ep = {}; ep.bias = dt_b; ep.f32o = dtb;
  mgemm_k<6,false><<<dim3(EMBED/MBM, BL/MBM), 256, 0, stream>>>(
      xdblb, DTR, 0, dtwb, DTR, 0, DTR, ep);

  // 2b. transpose V per chunk (xnb dead now)
  transpose_k<<<dim3(EMBED/64, BL/64), 256, 0, stream>>>(
      (const unsigned short*)vbufb, (unsigned short*)VT);

  // 5. segment-parallel scan -> mxb
  seg_scan_k<false><<<NSEG*8, 256, 0, stream>>>(xdbl, dtb, xn, A_log, D_p,
                                                nullptr, segP, segH, nullptr);
  seg_combine_k<<<128, 256, 0, stream>>>(segP, segH, segInit);
  seg_scan_k<true><<<NSEG*8, 256, 0, stream>>>(xdbl, dtb, xn, A_log, D_p,
                                               segInit, nullptr, nullptr, mxb);

  // 6. base = mx @ mx_w^T + mx_b, split epilogue
  ep = {}; ep.bias = mx_b; ep.gamma = gamma; ep.beta2 = beta;
  ep.ug = ugb; ep.qo = qb; ep.ko = kb; ep.ro = rbb; ep.hxo = hxbb;
  mgemm_k<1,false><<<dim3(3200/MBM, BL/MBM), 256, 0, stream>>>(
      mxb, EMBED, 0, mxwb, EMBED, 0, EMBED, ep);

  // 7. QK^T + bias + mask -> f32 S (upper-triangle tiles skipped)
  ep = {}; ep.gtab = gtab; ep.Sout = S;
  mgemm_k<2,false><<<dim3(CHUNKC/MBM, CHUNKC/MBM, 4), 256, 0, stream>>>(
      qb, ZD, (long long)CHUNKC*ZD, kb, ZD, (long long)CHUNKC*ZD, ZD, ep);

  // 8. softmax (causal-aware reads)
  softmax_k<<<4*CHUNKC, 256, 0, stream>>>(S, Sb);

  // 9. P@V, K clipped to diagonal, fused *r -> bf16
  ep = {}; ep.rb = rbb; ep.Cb = hrb;
  mgemm_k<3,true><<<dim3(EMBED/MBM, CHUNKC/MBM, 4), 256, 0, stream>>>(
      Sb, CHUNKC, (long long)CHUNKC*CHUNKC, VT, CHUNKC, (long long)EMBED*CHUNKC, CHUNKC, ep);

  // 10. final: h = silu(hx + (h*r) @ h_w^T + h_b); out = x + u*(h-x)
  ep = {}; ep.bias = h_b; ep.hxb = hxbb; ep.ub = ugb; ep.resid = x; ep.outp = out;
  mgemm_k<4,false><<<dim3(EMBED/MBM, BL/MBM), 256, 0, stream>>>(
      hrb, EMBED, 0, hwb, EMBED, 0, EMBED, ep);
}

// Round 5
// 514.407 us; speedup vs baseline: 7.7718x; 1.0074x over previous
//
#include <hip/hip_runtime.h>
#include <hip/hip_bf16.h>
#include <math.h>

#define EMBED 1024
#define LSEQ 4096
#define BATCH 2
#define ZD 128
#define CHUNKC 2048
#define NSTATE 16
#define DTR 64
#define XDBL_W 96   // DT_RANK + 2*DSTATE
#define NSEG 64
#define TSEG 64     // LSEQ / NSEG

typedef __attribute__((ext_vector_type(8))) short bf16x8;
typedef __attribute__((ext_vector_type(4))) float f32x4;

__device__ __forceinline__ float sigmoidf_(float x){ return 1.f/(1.f+__expf(-x)); }
__device__ __forceinline__ float siluf_(float x){ return x/(1.f+__expf(-x)); }
__device__ __forceinline__ __hip_bfloat16 tobf(float x){ return __float2bfloat16(x); }
__device__ __forceinline__ float frombf(__hip_bfloat16 x){ return __bfloat162float(x); }

__device__ __forceinline__ void gload_lds16(const void* g, void* l) {
  __builtin_amdgcn_global_load_lds(
      (const __attribute__((address_space(1))) unsigned int*)g,
      (__attribute__((address_space(3))) unsigned int*)l, 16, 0, 0);
}

// ---------------------------------------------------------------- f32 -> bf16 convert
__global__ __launch_bounds__(256) void cvt_k(const float* __restrict__ s,
                                             __hip_bfloat16* __restrict__ d, int n) {
  for (int i = (blockIdx.x*256 + threadIdx.x)*4; i < n; i += gridDim.x*256*4) {
    float4 v = *(const float4*)(s + i);
    d[i+0]=tobf(v.x); d[i+1]=tobf(v.y); d[i+2]=tobf(v.z); d[i+3]=tobf(v.w);
  }
}

// zero-padded convert (rows >= srcRows -> 0)
__global__ __launch_bounds__(256) void cvt_pad_k(const float* __restrict__ s,
                                                 __hip_bfloat16* __restrict__ d,
                                                 int srcRows, int cols, int dstRows) {
  int idx = blockIdx.x*256 + threadIdx.x;
  if (idx >= dstRows*cols) return;
  int r = idx / cols;
  d[idx] = tobf(r < srcRows ? s[idx] : 0.f);
}

// ---------------------------------------------------------------- rmsnorm (dual out: f32 + bf16)
__global__ __launch_bounds__(256) void rmsnorm_k(const float* __restrict__ x,
                                                 const float* __restrict__ w,
                                                 float* __restrict__ xn,
                                                 __hip_bfloat16* __restrict__ xnb) {
  size_t row = blockIdx.x;
  const float* px = x + row*EMBED;
  int tid = threadIdx.x;
  float4 xv = *(const float4*)(px + tid*4);
  float ss = xv.x*xv.x + xv.y*xv.y + xv.z*xv.z + xv.w*xv.w;
  #pragma unroll
  for (int off=32; off; off>>=1) ss += __shfl_down(ss, off, 64);
  __shared__ float red[4];
  if ((tid&63)==0) red[tid>>6]=ss;
  __syncthreads();
  float tot = red[0]+red[1]+red[2]+red[3];
  float scale = rsqrtf(tot*(1.f/EMBED) + 1e-5f);
  float4 wv = *(const float4*)(w + tid*4);
  float4 o;
  o.x=xv.x*scale*wv.x; o.y=xv.y*scale*wv.y; o.z=xv.z*scale*wv.z; o.w=xv.w*scale*wv.w;
  *(float4*)(xn + row*EMBED + tid*4) = o;
  __hip_bfloat16* pb = xnb + row*EMBED + tid*4;
  pb[0]=tobf(o.x); pb[1]=tobf(o.y); pb[2]=tobf(o.z); pb[3]=tobf(o.w);
}

// ---------------------------------------------------------------- gtab (Toeplitz rel-pos bias)
__global__ __launch_bounds__(256) void gtab_k(const float* __restrict__ alpha,
                                              const float* __restrict__ beta,
                                              float* __restrict__ gtab) {
  __shared__ float P[64], Q[64], F[64];
  int tid = threadIdx.x;
  if (tid < 64) {
    float a1=alpha[tid], a2=alpha[64+tid], b1=beta[tid], b2=beta[64+tid];
    P[tid]=a1*b1+a2*b2;
    Q[tid]=a2*b1-a1*b2;
    F[tid]=expf(-0.14391156831f*(float)tid); // ln(10000)/64
  }
  __syncthreads();
  int d = blockIdx.x*256 + tid;
  if (d < CHUNKC) {
    float s=0.f;
    for (int j=0;j<64;++j){
      float th = (float)d * F[j];
      float sn, cs;
      sincosf(th, &sn, &cs);
      s += P[j]*cs - Q[j]*sn;
    }
    gtab[d]=s;
  }
}

// ---------------------------------------------------------------- segment-parallel S6 scan
template<bool FINAL>
__global__ __launch_bounds__(256) void seg_scan_k(
    const float* __restrict__ xdbl,
    const float* __restrict__ dtv,
    const float* __restrict__ xn,
    const float* __restrict__ A_log,
    const float* __restrict__ D_p,
    const float* __restrict__ segInit,
    float* __restrict__ segP,
    float* __restrict__ segH,
    __hip_bfloat16* __restrict__ mx)
{
  int bx = blockIdx.x;
  int seg = bx >> 3;
  int grp = bx & 7;
  int b = grp >> 2;
  int d = (grp & 3)*256 + threadIdx.x;
  int ch = b*EMBED + d;
  int tid = threadIdx.x;
  int tbase = seg*TSEG;

  float A[NSTATE], h[NSTATE], P[NSTATE];
  #pragma unroll
  for (int n=0;n<NSTATE;++n){
    A[n] = -__expf(A_log[(size_t)d*NSTATE+n]);
    P[n] = 1.f;
  }
  if (FINAL) {
    const float* si = segInit + ((size_t)seg*2048 + ch)*NSTATE;
    #pragma unroll
    for (int n=0;n<NSTATE;++n) h[n] = si[n];
  } else {
    #pragma unroll
    for (int n=0;n<NSTATE;++n) h[n] = 0.f;
  }
  float Dp = FINAL ? D_p[d] : 0.f;

  __shared__ float BCb[8][32];
  const float* xd  = xdbl + ((size_t)b*LSEQ + tbase)*XDBL_W + DTR;
  const float* pdt = dtv + ((size_t)b*LSEQ + tbase)*EMBED + d;
  const float* pu  = xn  + ((size_t)b*LSEQ + tbase)*EMBED + d;
  __hip_bfloat16* pmx = mx + ((size_t)b*LSEQ + tbase)*EMBED + d;

  for (int t0=0; t0<TSEG; t0+=8) {
    __syncthreads();
    { int tt = tid>>5, jj = tid&31;
      BCb[tt][jj] = xd[(size_t)(t0+tt)*XDBL_W + jj]; }
    __syncthreads();
    #pragma unroll
    for (int tt=0; tt<8; ++tt) {
      int t = t0 + tt;
      float dtt = pdt[(size_t)t*EMBED];
      float ut  = pu[(size_t)t*EMBED];
      float du = dtt*ut;
      float y = 0.f;
      #pragma unroll
      for (int n=0;n<NSTATE;++n){
        float dA = __expf(dtt*A[n]);
        h[n] = dA*h[n] + du*BCb[tt][n];
        if (!FINAL) P[n] *= dA;
        if (FINAL)  y += h[n]*BCb[tt][16+n];
      }
      if (FINAL) pmx[(size_t)t*EMBED] = tobf(siluf_(y + ut*Dp));
    }
  }
  if (!FINAL) {
    float* pp = segP + ((size_t)seg*2048 + ch)*NSTATE;
    float* ph = segH + ((size_t)seg*2048 + ch)*NSTATE;
    #pragma unroll
    for (int n=0;n<NSTATE;n+=4){
      *(float4*)(pp+n) = make_float4(P[n],P[n+1],P[n+2],P[n+3]);
      *(float4*)(ph+n) = make_float4(h[n],h[n+1],h[n+2],h[n+3]);
    }
  }
}

__global__ __launch_bounds__(256) void seg_combine_k(const float* __restrict__ segP,
                                                     const float* __restrict__ segH,
                                                     float* __restrict__ segInit) {
  int idx = blockIdx.x*256 + threadIdx.x;
  float H = 0.f;
  for (int s=0; s<NSEG; ++s) {
    size_t o = (size_t)s*32768 + idx;
    float Pv = segP[o], hl = segH[o];
    segInit[o] = H;
    H = Pv*H + hl;
  }
}

// ---------------------------------------------------------------- row softmax (f32 in, bf16 out), causal-aware
__global__ __launch_bounds__(256) void softmax_k(const float* __restrict__ S,
                                                 __hip_bfloat16* __restrict__ Sb) {
  size_t row = blockIdx.x;
  const float* p = S + row*CHUNKC;
  __hip_bfloat16* po = Sb + row*CHUNKC;
  int tid = threadIdx.x;
  int r = (int)(row & (CHUNKC-1));
  int nb = (r >> 8) + 1;             // 256-wide column blocks that contain valid cols
  float v[8];
  float m = -1e30f;
  #pragma unroll
  for (int i=0;i<8;++i){
    if (i < nb) {
      float t = p[tid + i*256];
      v[i] = (i*256 + tid <= r) ? t : -1e30f;
    } else v[i] = -1e30f;
    m = fmaxf(m, v[i]);
  }
  #pragma unroll
  for (int off=32; off; off>>=1) m = fmaxf(m, __shfl_down(m, off, 64));
  __shared__ float red[4];
  if ((tid&63)==0) red[tid>>6]=m;
  __syncthreads();
  m = fmaxf(fmaxf(red[0],red[1]),fmaxf(red[2],red[3]));
  float s=0.f;
  #pragma unroll
  for (int i=0;i<8;++i){ v[i]=__expf(v[i]-m); s+=v[i]; }
  #pragma unroll
  for (int off=32; off; off>>=1) s += __shfl_down(s, off, 64);
  __syncthreads();
  if ((tid&63)==0) red[tid>>6]=s;
  __syncthreads();
  s = red[0]+red[1]+red[2]+red[3];
  float inv = 1.f/s;
  #pragma unroll
  for (int i=0;i<8;++i) po[tid + i*256] = tobf(v[i]*inv);
}

// ---------------------------------------------------------------- bf16 transpose V -> VT[c][n][k]
__global__ __launch_bounds__(256) void transpose_k(const unsigned short* __restrict__ vb,
                                                   unsigned short* __restrict__ VT) {
  __shared__ unsigned short t[64][68];
  int tid = threadIdx.x;
  int tr = tid>>4;          // 0..15
  int tc = (tid&15)*4;      // 0..60
  int c0 = blockIdx.x*64, r0 = blockIdx.y*64;
  #pragma unroll
  for (int it=0; it<4; ++it) {
    int r = it*16 + tr;
    ushort4 v = *(const ushort4*)(vb + (size_t)(r0+r)*EMBED + c0 + tc);
    t[r][tc+0]=v.x; t[r][tc+1]=v.y; t[r][tc+2]=v.z; t[r][tc+3]=v.w;
  }
  __syncthreads();
  int ch = r0 >> 11;
  int kb = r0 & 2047;
  #pragma unroll
  for (int it=0; it<4; ++it) {
    int nl = it*16 + tr;
    ushort4 o;
    o.x = t[tc+0][nl]; o.y = t[tc+1][nl]; o.z = t[tc+2][nl]; o.w = t[tc+3][nl];
    *(ushort4*)(VT + ((size_t)ch*EMBED + c0 + nl)*CHUNKC + kb + tc) = o;
  }
}

// ---------------------------------------------------------------- bf16 MFMA GEMM
// 128x128 tile, BK=64, double-buffered LDS, XOR-swizzled staging/reads,
// counted-vmcnt pipeline (loads stay in flight across raw s_barriers),
// bijective XCD-aware blockIdx swizzle (SWZ).
// C[m,n] = sum_k A[m,k]*B[n,k] (both row-major, k contiguous)
// EPI: 0 silu+bias->bf16; 1 base-split; 2 QK bias+mask->f32 (upper tiles skipped);
//      3 PV*r->bf16 (TRIK: K clipped to m0+128); 4 final gate->f32 out;
//      5 xdbl dual (f32 96 + bf16 64); 6 dt softplus->f32
struct MEp {
  const float* bias; const float* gtab; const float* gamma; const float* beta2;
  __hip_bfloat16* ug; __hip_bfloat16* qo; __hip_bfloat16* ko; __hip_bfloat16* ro; __hip_bfloat16* hxo;
  const __hip_bfloat16* rb; const __hip_bfloat16* hxb; const __hip_bfloat16* ub;
  const float* resid; float* outp; float* Sout;
  __hip_bfloat16* Cb; int ldc;
  float* f32o; __hip_bfloat16* bf16o;
};

#define MBM 128
#define MBK 64

template<int EPI, bool TRIK, bool SWZ>
__global__ __launch_bounds__(256) void mgemm_k(
    const __hip_bfloat16* __restrict__ A, int lda, long long sAz,
    const __hip_bfloat16* __restrict__ B, int ldb, long long sBz,
    int K, MEp ep)
{
  __shared__ __attribute__((aligned(16))) short As[2][MBM*MBK];
  __shared__ __attribute__((aligned(16))) short Bs[2][MBM*MBK];
  const int tid = threadIdx.x;
  const int wv = tid>>6, lane = tid&63;
  const int z = blockIdx.z;
  A += (size_t)z * sAz;
  B += (size_t)z * sBz;
  int bx = blockIdx.x, by = blockIdx.y;
  if constexpr (SWZ) {
    const int gx = gridDim.x;
    const int nwg = gx*gridDim.y;
    const int lin = by*gx + bx;              // hw dispatch id (round-robins XCDs)
    const int qq = nwg >> 3, rr = nwg & 7;
    const int xcd = lin & 7, pos = lin >> 3;
    const int base = (xcd < rr) ? xcd*(qq+1) : rr*(qq+1) + (xcd-rr)*qq;
    const int lg = base + pos;               // contiguous logical chunk per XCD
    bx = lg % gx; by = lg / gx;
  }
  const int m0 = by*MBM, n0 = bx*MBM;
  if constexpr (EPI==2) { if (n0 > m0 + (MBM-1)) return; }  // fully-masked tile
  const int r8 = lane>>3, g8 = lane&7;
  const int csrc = g8 ^ r8;               // inverse-swizzled source chunk
  const int wr = wv>>1, wc = wv&1;
  const int fr = lane&15, qv = lane>>4;
  const int x7 = fr & 7;

  int Ktot = K;
  if constexpr (TRIK) { int km = m0 + MBM; Ktot = km < K ? km : K; }
  const int nt = Ktot / MBK;

  f32x4 acc[4][4] = {};

  const __hip_bfloat16* Ag = A + (size_t)(m0 + wv*32 + r8)*lda + csrc*8;
  const __hip_bfloat16* Bg = B + (size_t)(n0 + wv*32 + r8)*ldb + csrc*8;

  auto stage = [&](int buf, int t){
    const int k0 = t*MBK;
    short* Al = &As[buf][wv*32*MBK];
    short* Bl = &Bs[buf][wv*32*MBK];
    #pragma unroll
    for (int j=0;j<4;++j)
      gload_lds16(Ag + (size_t)(j*8)*lda + k0, Al + j*8*MBK);
    #pragma unroll
    for (int j=0;j<4;++j)
      gload_lds16(Bg + (size_t)(j*8)*ldb + k0, Bl + j*8*MBK);
  };

  // prologue: fill both buffers, wait only buf0 (counted), never drain mid-loop
  stage(0, 0);
  if (nt > 1) {
    stage(1, 1);
    asm volatile("s_waitcnt vmcnt(8)" ::: "memory");
  } else {
    asm volatile("s_waitcnt vmcnt(0)" ::: "memory");
  }
  __builtin_amdgcn_sched_barrier(0);
  __builtin_amdgcn_s_barrier();

  for (int t=0; t<nt; ++t) {
    const int cur = t & 1;
    const short* Ab = &As[cur][0];
    const short* Bb = &Bs[cur][0];
    #pragma unroll
    for (int kk=0; kk<2; ++kk) {
      const int pos8 = ((kk*4 + qv) ^ x7) * 8;   // swizzled 16B-chunk within row
      bf16x8 af[4], bfr[4];
      #pragma unroll
      for (int mi=0;mi<4;++mi)
        af[mi] = *(const bf16x8*)&Ab[(wr*64 + mi*16 + fr)*MBK + pos8];
      #pragma unroll
      for (int ni=0;ni<4;++ni)
        bfr[ni] = *(const bf16x8*)&Bb[(wc*64 + ni*16 + fr)*MBK + pos8];
      #pragma unroll
      for (int mi=0;mi<4;++mi)
        #pragma unroll
        for (int ni=0;ni<4;++ni)
          acc[mi][ni] = __builtin_amdgcn_mfma_f32_16x16x32_bf16(af[mi], bfr[ni], acc[mi][ni], 0,0,0);
    }
    if (t+1 >= nt) break;
    __builtin_amdgcn_sched_barrier(0);
    __builtin_amdgcn_s_barrier();            // A: all waves done reading buf[cur]
    if (t+2 < nt) {
      stage(cur, t+2);                       // overwrite freed buffer
      asm volatile("s_waitcnt vmcnt(8)" ::: "memory");   // t+1's loads done; t+2's stay in flight
    } else {
      asm volatile("s_waitcnt vmcnt(0)" ::: "memory");   // final tile drain
    }
    __builtin_amdgcn_sched_barrier(0);
    __builtin_amdgcn_s_barrier();            // B: buf[cur^1] ready on all waves
  }

  const int vr = (lane>>4)*4;
  #pragma unroll
  for (int mi=0;mi<4;++mi) {
    #pragma unroll
    for (int v=0; v<4; ++v) {
      const int row = m0 + wr*64 + mi*16 + vr + v;
      #pragma unroll
      for (int ni=0;ni<4;++ni) {
        const int col = n0 + wc*64 + ni*16 + fr;
        float val = acc[mi][ni][v];
        if constexpr (EPI==0) {
          ep.Cb[(size_t)row*ep.ldc + col] = tobf(siluf_(val + ep.bias[col]));
        } else if constexpr (EPI==1) {
          val += ep.bias[col];
          if (col < 1024) {
            ep.ug[(size_t)row*EMBED + col] = tobf(sigmoidf_(val));
          } else if (col < 1152) {
            int jj = col - 1024;
            float zz = siluf_(val);
            ep.qo[(size_t)row*ZD + jj] = tobf((zz*ep.gamma[jj] + ep.beta2[jj]) * 0.08838834764831845f);
            ep.ko[(size_t)row*ZD + jj] = tobf(zz*ep.gamma[128+jj] + ep.beta2[128+jj]);
          } else if (col < 2176) {
            ep.ro[(size_t)row*EMBED + (col-1152)] = tobf(siluf_(val));
          } else {
            ep.hxo[(size_t)row*EMBED + (col-2176)] = tobf(val);
          }
        } else if constexpr (EPI==2) {
          float* Sp = ep.Sout + (size_t)z*CHUNKC*CHUNKC;
          Sp[(size_t)row*CHUNKC + col] = (col <= row) ? val + ep.gtab[row-col] : -1e30f;
        } else if constexpr (EPI==3) {
          size_t gr = (size_t)z*CHUNKC + row;
          ep.Cb[gr*EMBED + col] = tobf(val * frombf(ep.rb[gr*EMBED + col]));
        } else if constexpr (EPI==4) {
          float zz = val + ep.bias[col] + frombf(ep.hxb[(size_t)row*EMBED + col]);
          float hh = siluf_(zz);
          float res = ep.resid[(size_t)row*EMBED + col];
          ep.outp[(size_t)row*EMBED + col] = res + frombf(ep.ub[(size_t)row*EMBED + col])*(hh-res);
        } else if constexpr (EPI==5) {
          if (col < XDBL_W) ep.f32o[(size_t)row*XDBL_W + col] = val;
          if (col < DTR)    ep.bf16o[(size_t)row*DTR + col] = tobf(val);
        } else {
          float zv = val + ep.bias[col];
          ep.f32o[(size_t)row*EMBED + col] = (zv > 15.f) ? zv : log1pf(__expf(zv));
        }
      }
    }
  }
}

// ---------------------------------------------------------------- launch
extern "C" void kernel_launch(void* const* d_in, const int* in_sizes, int n_in,
                              void* d_out, int out_size, void* d_ws, size_t ws_size,
                              hipStream_t stream) {
  const float* x       = (const float*)d_in[0];
  const float* norm_w  = (const float*)d_in[1];
  const float* v_w     = (const float*)d_in[2];
  const float* v_b     = (const float*)d_in[3];
  const float* mx_w    = (const float*)d_in[4];
  const float* mx_b    = (const float*)d_in[5];
  const float* h_w     = (const float*)d_in[6];
  const float* h_b     = (const float*)d_in[7];
  const float* gamma   = (const float*)d_in[8];
  const float* beta    = (const float*)d_in[9];
  const float* alpha_rb= (const float*)d_in[10];
  const float* beta_rb = (const float*)d_in[11];
  const float* xproj_w = (const float*)d_in[12];
  const float* dt_w    = (const float*)d_in[13];
  const float* dt_b    = (const float*)d_in[14];
  const float* A_log   = (const float*)d_in[15];
  const float* D_p     = (const float*)d_in[16];
  float* out = (float*)d_out;

  float* ws = (float*)d_ws;
  size_t off = 0;
  auto alloc = [&](size_t n){ float* p = ws + off; off += n; return p; };
  const size_t BL = (size_t)BATCH*LSEQ; // 8192

  float* xn      = alloc(BL*EMBED);        // f32; later aliased by Sb
  float* scratch = alloc((size_t)2*CHUNKC*CHUNKC*2); // 16.78M f32: dtb+seg*, then S
  float* xdbl    = alloc(BL*XDBL_W);
  float* gtab    = alloc(CHUNKC);
  auto balloc = [&](size_t nbf){ __hip_bfloat16* p = (__hip_bfloat16*)(ws + off); off += (nbf+1)/2; return p; };
  __hip_bfloat16* xnb   = balloc(BL*EMBED);   // later reused as VT
  __hip_bfloat16* vbufb = balloc(BL*EMBED);
  __hip_bfloat16* mxb   = balloc(BL*EMBED);
  __hip_bfloat16* qb    = balloc(BL*ZD);
  __hip_bfloat16* kb    = balloc(BL*ZD);
  __hip_bfloat16* ugb   = balloc(BL*EMBED);
  __hip_bfloat16* rbb   = balloc(BL*EMBED);
  __hip_bfloat16* hxbb  = balloc(BL*EMBED);
  __hip_bfloat16* hrb   = balloc(BL*EMBED);
  __hip_bfloat16* xdblb = balloc(BL*DTR);
  __hip_bfloat16* vwb   = balloc((size_t)EMBED*EMBED);
  __hip_bfloat16* mxwb  = balloc((size_t)3200*EMBED);
  __hip_bfloat16* hwb   = balloc((size_t)EMBED*EMBED);
  __hip_bfloat16* xpwb  = balloc((size_t)128*EMBED);   // xproj_w padded 96->128 rows
  __hip_bfloat16* dtwb  = balloc((size_t)EMBED*DTR);

  float* dtb     = scratch;
  float* segP    = scratch + BL*EMBED;
  float* segH    = segP + (size_t)NSEG*2048*NSTATE;
  float* segInit = segH + (size_t)NSEG*2048*NSTATE;
  float* S  = scratch;                      // after scan
  __hip_bfloat16* Sb = (__hip_bfloat16*)xn; // after scan
  __hip_bfloat16* VT = xnb;                 // after v + xdbl GEMMs

  // 0. weight conversions + bias table
  cvt_k<<<512, 256, 0, stream>>>(v_w,  vwb,  EMBED*EMBED);
  cvt_k<<<512, 256, 0, stream>>>(mx_w, mxwb, 3200*EMBED);
  cvt_k<<<512, 256, 0, stream>>>(h_w,  hwb,  EMBED*EMBED);
  cvt_k<<<64,  256, 0, stream>>>(dt_w, dtwb, EMBED*DTR);
  cvt_pad_k<<<(128*EMBED+255)/256, 256, 0, stream>>>(xproj_w, xpwb, XDBL_W, EMBED, 128);
  gtab_k<<<CHUNKC/256, 256, 0, stream>>>(alpha_rb, beta_rb, gtab);

  // 1. rmsnorm
  rmsnorm_k<<<(int)BL, 256, 0, stream>>>(x, norm_w, xn, xnb);

  MEp ep;

  // 2. v = silu(xn @ v_w^T + v_b)  [bf16]
  ep = {}; ep.bias = v_b; ep.Cb = vbufb; ep.ldc = EMBED;
  mgemm_k<0,false,true><<<dim3(EMBED/MBM, BL/MBM), 256, 0, stream>>>(
      xnb, EMBED, 0, vwb, EMBED, 0, EMBED, ep);

  // 3. xdbl = xn @ xproj_w^T  (f32 96 cols + bf16 first 64)
  ep = {}; ep.f32o = xdbl; ep.bf16o = xdblb;
  mgemm_k<5,false,false><<<dim3(1, BL/MBM), 256, 0, stream>>>(
      xnb, EMBED, 0, xpwb, EMBED, 0, EMBED, ep);

  // 4. dt = softplus(xdbl[:, :64] @ dt_w^T + dt_b)  (f32)
  ep = {}; ep.bias = dt_b; ep.f32o = dtb;
  mgemm_k<6,false,true><<<dim3(EMBED/MBM, BL/MBM), 256, 0, stream>>>(
      xdblb, DTR, 0, dtwb, DTR, 0, DTR, ep);

  // 2b. transpose V per chunk (xnb dead now)
  transpose_k<<<dim3(EMBED/64, BL/64), 256, 0, stream>>>(
      (const unsigned short*)vbufb, (unsigned short*)VT);

  // 5. segment-parallel scan -> mxb
  seg_scan_k<false><<<NSEG*8, 256, 0, stream>>>(xdbl, dtb, xn, A_log, D_p,
                                                nullptr, segP, segH, nullptr);
  seg_combine_k<<<128, 256, 0, stream>>>(segP, segH, segInit);
  seg_scan_k<true><<<NSEG*8, 256, 0, stream>>>(xdbl, dtb, xn, A_log, D_p,
                                               segInit, nullptr, nullptr, mxb);

  // 6. base = mx @ mx_w^T + mx_b, split epilogue
  ep = {}; ep.bias = mx_b; ep.gamma = gamma; ep.beta2 = beta;
  ep.ug = ugb; ep.qo = qb; ep.ko = kb; ep.ro = rbb; ep.hxo = hxbb;
  mgemm_k<1,false,true><<<dim3(3200/MBM, BL/MBM), 256, 0, stream>>>(
      mxb, EMBED, 0, mxwb, EMBED, 0, EMBED, ep);

  // 7. QK^T + bias + mask -> f32 S (upper-triangle tiles skipped)
  ep = {}; ep.gtab = gtab; ep.Sout = S;
  mgemm_k<2,false,true><<<dim3(CHUNKC/MBM, CHUNKC/MBM, 4), 256, 0, stream>>>(
      qb, ZD, (long long)CHUNKC*ZD, kb, ZD, (long long)CHUNKC*ZD, ZD, ep);

  // 8. softmax (causal-aware reads)
  softmax_k<<<4*CHUNKC, 256, 0, stream>>>(S, Sb);

  // 9. P@V, K clipped to diagonal, fused *r -> bf16
  ep = {}; ep.rb = rbb; ep.Cb = hrb;
  mgemm_k<3,true,true><<<dim3(EMBED/MBM, CHUNKC/MBM, 4), 256, 0, stream>>>(
      Sb, CHUNKC, (long long)CHUNKC*CHUNKC, VT, CHUNKC, (long long)EMBED*CHUNKC, CHUNKC, ep);

  // 10. final: h = silu(hx + (h*r) @ h_w^T + h_b); out = x + u*(h-x)
  ep = {}; ep.bias = h_b; ep.hxb = hxbb; ep.ub = ugb; ep.resid = x; ep.outp = out;
  mgemm_k<4,false,true><<<dim3(EMBED/MBM, BL/MBM), 256, 0, stream>>>(
      hrb, EMBED, 0, hwb, EMBED, 0, EMBED, ep);
}